// Round 1
// baseline (5951.217 us; speedup 1.0000x reference)
//
#include <hip/hip_runtime.h>
#include <math.h>

// Problem constants
#define NROWS 25600   // N = B*SEQ = 1024*25
#define DCH   128     // D
#define SEQL  25
#define NHEAD 8
#define EPSV  1e-6f

// ---------------- Cl(3,0) geometric product ----------------
// blade order [1, e1, e2, e3, e12, e13, e23, e123]
// index->bitmask and bitmask->index are the same involution {0,1,2,4,3,5,6,7}
__device__ __forceinline__ void gprod(const float* a, const float* b, float* r) {
  const int M[8] = {0,1,2,4,3,5,6,7}; // blade index -> mask
  const int P[8] = {0,1,2,4,3,5,6,7}; // mask -> blade index
#pragma unroll
  for (int i = 0; i < 8; ++i) {
    const int ma = M[i];
#pragma unroll
    for (int k = 0; k < 8; ++k) {
      const int mb = M[k];
      int par = 0;
      for (int t = ma >> 1; t; t >>= 1) par += __popc(t & mb);
      const float s = (par & 1) ? -1.f : 1.f;
      r[P[ma ^ mb]] += s * a[i] * b[k];
    }
  }
}

// ---------------- block-wide mean-of-multivector-norms ----------------
// row: C*8 floats (LDS or global), red: 256-float LDS scratch.
// Returns mean_c ||row[c,:]|| + EPS on all 256 threads.
__device__ __forceinline__ float row_norm_mean(const float* row, float* red, int C) {
  const int tid = threadIdx.x;
  float p = 0.f;
  for (int c = tid; c < C; c += 256) {
    const float* e = row + c * 8;
    float s = 0.f;
#pragma unroll
    for (int i = 0; i < 8; ++i) s += e[i] * e[i];
    p += sqrtf(s);
  }
  red[tid] = p;
  __syncthreads();
  for (int off = 128; off > 0; off >>= 1) {
    if (tid < off) red[tid] += red[tid + off];
    __syncthreads();
  }
  float v = red[0] / (float)C + EPSV;
  __syncthreads();
  return v;
}

// ---------------- K1: per-row mean multivector norm of src ----------------
__global__ __launch_bounds__(256) void norms_kernel(const float* __restrict__ x,
                                                    float* __restrict__ nm) {
  __shared__ float red[256];
  const int n = blockIdx.x;
  float v = row_norm_mean(x + (size_t)n * DCH * 8, red, DCH);
  if (threadIdx.x == 0) nm[n] = v;
}

// ---------------- K2: generic mv_linear (optionally LN-folded input, residual) ----
// y[n,o,i] = (LNIN? 1/nm[n] : 1) * sum_m (LNIN? a[m] : 1)*x[n,m,i] * w[o,m,g(i)]
//            + (i==0)*bias[o] + (RES? res_a[o]/res_nm[n]*res[n,o,i] : 0)
// x may be split in two halves (xhi != null -> channels >= IC/2 from xhi),
// y may be split (yhi != null, OC==256 -> channels >= 128 to yhi).
template <int IC, int OC, bool LNIN, bool RES>
__global__ __launch_bounds__(256) void mvlin_kernel(
    const float* __restrict__ x, const float* __restrict__ xhi,
    const float* __restrict__ w, const float* __restrict__ bias,
    const float* __restrict__ a_in, const float* __restrict__ nm_in,
    const float* __restrict__ res, const float* __restrict__ res_a,
    const float* __restrict__ res_nm,
    float* __restrict__ y, float* __restrict__ yhi) {
  constexpr int TN = 4;
  constexpr int RS = IC * 8;
  __shared__ __align__(16) float xs[TN][RS];
  const int tid = threadIdx.x;
  const int n0 = blockIdx.x * TN;

  float inv[TN];
#pragma unroll
  for (int r = 0; r < TN; ++r) inv[r] = LNIN ? 1.0f / nm_in[n0 + r] : 1.0f;

  const size_t xstride = xhi ? (size_t)(IC / 2) * 8 : (size_t)IC * 8;
  for (int idx = tid; idx < TN * RS; idx += 256) {
    const int r = idx / RS;
    const int rem = idx - r * RS;
    const int m = rem >> 3;
    const float* xp = x;
    int mm = m;
    if (xhi && m >= IC / 2) { xp = xhi; mm = m - IC / 2; }
    float v = xp[(size_t)(n0 + r) * xstride + mm * 8 + (rem & 7)];
    if (LNIN) v *= a_in[m] * inv[r];
    xs[r][rem] = v;
  }
  __syncthreads();

  if (OC == 128) {
    const int o = tid & 127;
    const int ig = tid >> 7; // 0: blades 0..3, 1: blades 4..7
    float acc[TN][4];
#pragma unroll
    for (int r = 0; r < TN; ++r) { acc[r][0] = acc[r][1] = acc[r][2] = acc[r][3] = 0.f; }
    const float4* w4 = reinterpret_cast<const float4*>(w) + (size_t)o * IC;
    for (int m = 0; m < IC; ++m) {
      const float4 wv = w4[m];
      const float w0 = ig ? wv.z : wv.x;
      const float wm = ig ? wv.z : wv.y;
      const float w3 = ig ? wv.w : wv.y;
#pragma unroll
      for (int r = 0; r < TN; ++r) {
        const float* xr = &xs[r][m * 8 + ig * 4];
        acc[r][0] += xr[0] * w0;
        acc[r][1] += xr[1] * wm;
        acc[r][2] += xr[2] * wm;
        acc[r][3] += xr[3] * w3;
      }
    }
#pragma unroll
    for (int r = 0; r < TN; ++r) {
      const int n = n0 + r;
      if (ig == 0) acc[r][0] += bias[o];
      if (RES) {
        const float rs = res_a[o] / res_nm[n];
        const float* rp = res + (size_t)n * (128 * 8) + o * 8 + ig * 4;
        acc[r][0] += rs * rp[0]; acc[r][1] += rs * rp[1];
        acc[r][2] += rs * rp[2]; acc[r][3] += rs * rp[3];
      }
      float4 ov; ov.x = acc[r][0]; ov.y = acc[r][1]; ov.z = acc[r][2]; ov.w = acc[r][3];
      *reinterpret_cast<float4*>(y + (size_t)n * (OC * 8) + o * 8 + ig * 4) = ov;
    }
  } else { // OC == 256
    const int o = tid;
    float acc[TN][8];
#pragma unroll
    for (int r = 0; r < TN; ++r)
#pragma unroll
      for (int j = 0; j < 8; ++j) acc[r][j] = 0.f;
    const float4* w4 = reinterpret_cast<const float4*>(w) + (size_t)o * IC;
    for (int m = 0; m < IC; ++m) {
      const float4 wv = w4[m];
#pragma unroll
      for (int r = 0; r < TN; ++r) {
        const float* xr = &xs[r][m * 8];
        acc[r][0] += xr[0] * wv.x;
        acc[r][1] += xr[1] * wv.y;
        acc[r][2] += xr[2] * wv.y;
        acc[r][3] += xr[3] * wv.y;
        acc[r][4] += xr[4] * wv.z;
        acc[r][5] += xr[5] * wv.z;
        acc[r][6] += xr[6] * wv.z;
        acc[r][7] += xr[7] * wv.w;
      }
    }
    float* yp = y;
    int oo = o;
    size_t ystride = (size_t)OC * 8;
    if (yhi) { ystride = 128 * 8; if (o >= 128) { yp = yhi; oo = o - 128; } }
#pragma unroll
    for (int r = 0; r < TN; ++r) {
      const int n = n0 + r;
      acc[r][0] += bias[o];
      float4 lo, hi;
      lo.x = acc[r][0]; lo.y = acc[r][1]; lo.z = acc[r][2]; lo.w = acc[r][3];
      hi.x = acc[r][4]; hi.y = acc[r][5]; hi.z = acc[r][6]; hi.w = acc[r][7];
      *reinterpret_cast<float4*>(yp + (size_t)n * ystride + oo * 8) = lo;
      *reinterpret_cast<float4*>(yp + (size_t)n * ystride + oo * 8 + 4) = hi;
    }
  }
}

// ---------------- K3: attention per (b,h), o overwrites q in place ----------
__global__ __launch_bounds__(256) void attn_kernel(float* __restrict__ q,
                                                   const float* __restrict__ k,
                                                   const float* __restrict__ v) {
  __shared__ __align__(16) float qs[SEQL * 128];
  __shared__ __align__(16) float ks[SEQL * 128];
  __shared__ __align__(16) float vs[SEQL * 128];
  __shared__ float ss[SEQL][SEQL];
  const int tid = threadIdx.x;
  const int b = blockIdx.x >> 3;
  const int h = blockIdx.x & 7;
  const size_t base = (size_t)b * SEQL * 1024 + (size_t)h * 128;

  for (int idx = tid; idx < SEQL * 128; idx += 256) {
    const int s = idx >> 7;
    const int rr = idx & 127;
    const size_t g = base + (size_t)s * 1024 + rr;
    qs[idx] = q[g]; ks[idx] = k[g]; vs[idx] = v[g];
  }
  __syncthreads();

  const float scale = 0.08838834764831845f; // 1/sqrt(128)
  for (int p = tid; p < SEQL * SEQL; p += 256) {
    const int s = p / SEQL;
    const int t = p - s * SEQL;
    float acc = 0.f;
    for (int j = 0; j < 128; ++j) acc += qs[s * 128 + j] * ks[t * 128 + j];
    ss[s][t] = acc * scale;
  }
  __syncthreads();

  if (tid < SEQL) {
    float m = -1e30f;
    for (int t = 0; t < SEQL; ++t) m = fmaxf(m, ss[tid][t]);
    float sum = 0.f;
    for (int t = 0; t < SEQL; ++t) { const float e = expf(ss[tid][t] - m); ss[tid][t] = e; sum += e; }
    const float isum = 1.f / sum;
    for (int t = 0; t < SEQL; ++t) ss[tid][t] *= isum;
  }
  __syncthreads();

  for (int idx = tid; idx < SEQL * 128; idx += 256) {
    const int s = idx >> 7;
    const int rr = idx & 127;
    float acc = 0.f;
#pragma unroll
    for (int t = 0; t < SEQL; ++t) acc += ss[s][t] * vs[t * 128 + rr];
    q[base + (size_t)s * 1024 + rr] = acc; // in place over q
  }
}

// ---------------- K4: xres = src + mv_linear(o, wo, bo); nm2 = rownorm(xres) ----
__global__ __launch_bounds__(256) void attnout_kernel(
    const float* __restrict__ o_in, const float* __restrict__ wo,
    const float* __restrict__ bo, const float* __restrict__ src,
    float* __restrict__ xres, float* __restrict__ nm2) {
  constexpr int TN = 4;
  __shared__ __align__(16) float xs[TN][1024];
  __shared__ __align__(16) float ys[TN][1024];
  __shared__ float red[256];
  const int tid = threadIdx.x;
  const int n0 = blockIdx.x * TN;

  for (int idx = tid; idx < TN * 1024; idx += 256) {
    const int r = idx >> 10;
    xs[r][idx & 1023] = o_in[(size_t)(n0 + r) * 1024 + (idx & 1023)];
  }
  __syncthreads();

  const int o = tid & 127;
  const int ig = tid >> 7;
  float acc[TN][4];
#pragma unroll
  for (int r = 0; r < TN; ++r) { acc[r][0] = acc[r][1] = acc[r][2] = acc[r][3] = 0.f; }
  const float4* w4 = reinterpret_cast<const float4*>(wo) + (size_t)o * 128;
  for (int m = 0; m < 128; ++m) {
    const float4 wv = w4[m];
    const float w0 = ig ? wv.z : wv.x;
    const float wm = ig ? wv.z : wv.y;
    const float w3 = ig ? wv.w : wv.y;
#pragma unroll
    for (int r = 0; r < TN; ++r) {
      const float* xr = &xs[r][m * 8 + ig * 4];
      acc[r][0] += xr[0] * w0;
      acc[r][1] += xr[1] * wm;
      acc[r][2] += xr[2] * wm;
      acc[r][3] += xr[3] * w3;
    }
  }
#pragma unroll
  for (int r = 0; r < TN; ++r) {
    const int n = n0 + r;
    if (ig == 0) acc[r][0] += bo[o];
    const float* sp = src + (size_t)n * 1024 + o * 8 + ig * 4;
    float4 ov;
    ov.x = acc[r][0] + sp[0]; ov.y = acc[r][1] + sp[1];
    ov.z = acc[r][2] + sp[2]; ov.w = acc[r][3] + sp[3];
    *reinterpret_cast<float4*>(&ys[r][o * 8 + ig * 4]) = ov;
    *reinterpret_cast<float4*>(xres + (size_t)n * 1024 + o * 8 + ig * 4) = ov;
  }
  __syncthreads();
  for (int r = 0; r < TN; ++r) {
    const float nmv = row_norm_mean(ys[r], red, 128);
    if (tid == 0) nm2[n0 + r] = nmv;
  }
}

// ---------------- K5: fused xl/xr mv_linears (LN2-folded) + geometric product ----
__global__ __launch_bounds__(256) void gp_kernel(
    const float* __restrict__ xres, const float* __restrict__ nm2,
    const float* __restrict__ ln2a,
    const float* __restrict__ gw1, const float* __restrict__ gb1,
    const float* __restrict__ gw2, const float* __restrict__ gb2,
    float* __restrict__ gplo, float* __restrict__ gphi) {
  constexpr int TN = 4;
  __shared__ __align__(16) float xs[TN][1024];
  const int tid = threadIdx.x;
  const int n0 = blockIdx.x * TN;
  float inv[TN];
#pragma unroll
  for (int r = 0; r < TN; ++r) inv[r] = 1.f / nm2[n0 + r];
  for (int idx = tid; idx < TN * 1024; idx += 256) {
    const int r = idx >> 10;
    const int rem = idx & 1023;
    xs[r][rem] = ln2a[rem >> 3] * xres[(size_t)(n0 + r) * 1024 + rem] * inv[r];
  }
  __syncthreads();

  const int c = tid; // 0..255 output channel
  float al[TN][8], ar[TN][8];
#pragma unroll
  for (int r = 0; r < TN; ++r)
#pragma unroll
    for (int j = 0; j < 8; ++j) { al[r][j] = 0.f; ar[r][j] = 0.f; }
  const float4* w1 = reinterpret_cast<const float4*>(gw1) + (size_t)c * 128;
  const float4* w2 = reinterpret_cast<const float4*>(gw2) + (size_t)c * 128;
  for (int m = 0; m < 128; ++m) {
    const float4 a4 = w1[m];
    const float4 b4 = w2[m];
#pragma unroll
    for (int r = 0; r < TN; ++r) {
      const float* xr = &xs[r][m * 8];
      al[r][0] += xr[0] * a4.x;
      al[r][1] += xr[1] * a4.y; al[r][2] += xr[2] * a4.y; al[r][3] += xr[3] * a4.y;
      al[r][4] += xr[4] * a4.z; al[r][5] += xr[5] * a4.z; al[r][6] += xr[6] * a4.z;
      al[r][7] += xr[7] * a4.w;
      ar[r][0] += xr[0] * b4.x;
      ar[r][1] += xr[1] * b4.y; ar[r][2] += xr[2] * b4.y; ar[r][3] += xr[3] * b4.y;
      ar[r][4] += xr[4] * b4.z; ar[r][5] += xr[5] * b4.z; ar[r][6] += xr[6] * b4.z;
      ar[r][7] += xr[7] * b4.w;
    }
  }
  float* yp = (c < 128) ? gplo : gphi;
  const int cc = (c < 128) ? c : c - 128;
#pragma unroll
  for (int r = 0; r < TN; ++r) {
    al[r][0] += gb1[c];
    ar[r][0] += gb2[c];
    float res[8] = {0.f, 0.f, 0.f, 0.f, 0.f, 0.f, 0.f, 0.f};
    gprod(al[r], ar[r], res);
    float4 lo, hi;
    lo.x = res[0]; lo.y = res[1]; lo.z = res[2]; lo.w = res[3];
    hi.x = res[4]; hi.y = res[5]; hi.z = res[6]; hi.w = res[7];
    *reinterpret_cast<float4*>(yp + (size_t)(n0 + r) * 1024 + cc * 8) = lo;
    *reinterpret_cast<float4*>(yp + (size_t)(n0 + r) * 1024 + cc * 8 + 4) = hi;
  }
}

// ---------------- K6: gl = mv_linear(gp, gw3, gb3); g = LN(gl, gna);
//                 x3 = ln2(xres) + g (in place over xres); nm4 = rownorm(x3) ----
__global__ __launch_bounds__(256) void glx3_kernel(
    const float* __restrict__ gplo, const float* __restrict__ gphi,
    const float* __restrict__ gw3, const float* __restrict__ gb3,
    const float* __restrict__ gna, const float* __restrict__ ln2a,
    const float* __restrict__ nm2, float* __restrict__ xbuf,
    float* __restrict__ nm4) {
  constexpr int TN = 4;
  __shared__ __align__(16) float xs[TN][2048];
  __shared__ __align__(16) float ys[TN][1024];
  __shared__ float red[256];
  const int tid = threadIdx.x;
  const int n0 = blockIdx.x * TN;

  for (int idx = tid; idx < TN * 2048; idx += 256) {
    const int r = idx >> 11;
    const int rem = idx & 2047;
    xs[r][rem] = (rem < 1024) ? gplo[(size_t)(n0 + r) * 1024 + rem]
                              : gphi[(size_t)(n0 + r) * 1024 + (rem - 1024)];
  }
  __syncthreads();

  const int o = tid & 127;
  const int ig = tid >> 7;
  float acc[TN][4];
#pragma unroll
  for (int r = 0; r < TN; ++r) { acc[r][0] = acc[r][1] = acc[r][2] = acc[r][3] = 0.f; }
  const float4* w4 = reinterpret_cast<const float4*>(gw3) + (size_t)o * 256;
  for (int m = 0; m < 256; ++m) {
    const float4 wv = w4[m];
    const float w0 = ig ? wv.z : wv.x;
    const float wm = ig ? wv.z : wv.y;
    const float w3 = ig ? wv.w : wv.y;
#pragma unroll
    for (int r = 0; r < TN; ++r) {
      const float* xr = &xs[r][m * 8 + ig * 4];
      acc[r][0] += xr[0] * w0;
      acc[r][1] += xr[1] * wm;
      acc[r][2] += xr[2] * wm;
      acc[r][3] += xr[3] * w3;
    }
  }
#pragma unroll
  for (int r = 0; r < TN; ++r) {
    if (ig == 0) acc[r][0] += gb3[o];
    float4 ov; ov.x = acc[r][0]; ov.y = acc[r][1]; ov.z = acc[r][2]; ov.w = acc[r][3];
    *reinterpret_cast<float4*>(&ys[r][o * 8 + ig * 4]) = ov;
  }
  __syncthreads();

  float inv2[TN];
#pragma unroll
  for (int r = 0; r < TN; ++r) inv2[r] = 1.f / nm2[n0 + r];

  for (int r = 0; r < TN; ++r) {
    const float nmg = row_norm_mean(ys[r], red, 128); // includes sync before reuse
    const float invg = 1.f / nmg;
    for (int idx = tid; idx < 1024; idx += 256) {
      const int cc = idx >> 3;
      const float v = ln2a[cc] * xbuf[(size_t)(n0 + r) * 1024 + idx] * inv2[r]
                    + gna[cc] * ys[r][idx] * invg;
      ys[r][idx] = v;
      xbuf[(size_t)(n0 + r) * 1024 + idx] = v;
    }
    __syncthreads();
    const float nmv = row_norm_mean(ys[r], red, 128);
    if (tid == 0) nm4[n0 + r] = nmv;
  }
}

// ---------------- K7: MVSiLU in place on one 128-channel half ----------------
__global__ __launch_bounds__(256) void silu_kernel(float* __restrict__ h,
                                                   const float* __restrict__ sa,
                                                   const float* __restrict__ sb) {
  const size_t idx = (size_t)blockIdx.x * 256 + threadIdx.x; // one (n,c)
  const int c = (int)(idx & 127);
  float* p = h + idx * 8;
  float4 lo = *reinterpret_cast<float4*>(p);
  float4 hi = *reinterpret_cast<float4*>(p + 4);
  const float i0 = lo.x;
  const float i1 = lo.y * lo.y + lo.z * lo.z + lo.w * lo.w;
  const float i2 = hi.x * hi.x + hi.y * hi.y + hi.z * hi.z;
  const float i3 = hi.w * hi.w;
  const float* sac = sa + c * 4;
  const float* sbc = sb + c * 4;
  const float g0 = 1.f / (1.f + expf(-(sac[0] * i0 + sbc[0])));
  const float g1 = 1.f / (1.f + expf(-(sac[1] * i1 + sbc[1])));
  const float g2 = 1.f / (1.f + expf(-(sac[2] * i2 + sbc[2])));
  const float g3 = 1.f / (1.f + expf(-(sac[3] * i3 + sbc[3])));
  lo.x *= g0; lo.y *= g1; lo.z *= g1; lo.w *= g1;
  hi.x *= g2; hi.y *= g2; hi.z *= g2; hi.w *= g3;
  *reinterpret_cast<float4*>(p) = lo;
  *reinterpret_cast<float4*>(p + 4) = hi;
}

// ---------------- launch ----------------
extern "C" void kernel_launch(void* const* d_in, const int* in_sizes, int n_in,
                              void* d_out, int out_size, void* d_ws, size_t ws_size,
                              hipStream_t stream) {
  (void)in_sizes; (void)n_in; (void)out_size; (void)ws_size;
  const float* src   = (const float*)d_in[0];
  const float* ln1_a = (const float*)d_in[1];
  const float* ln2_a = (const float*)d_in[2];
  const float* ln3_a = (const float*)d_in[3];
  const float* wq = (const float*)d_in[4];  const float* bq = (const float*)d_in[5];
  const float* wk = (const float*)d_in[6];  const float* bk = (const float*)d_in[7];
  const float* wv = (const float*)d_in[8];  const float* bv = (const float*)d_in[9];
  const float* wo = (const float*)d_in[10]; const float* bo = (const float*)d_in[11];
  const float* gw1 = (const float*)d_in[12]; const float* gb1 = (const float*)d_in[13];
  const float* gw2 = (const float*)d_in[14]; const float* gb2 = (const float*)d_in[15];
  const float* gw3 = (const float*)d_in[16]; const float* gb3 = (const float*)d_in[17];
  const float* gna = (const float*)d_in[18];
  const float* mw1 = (const float*)d_in[19]; const float* mb1 = (const float*)d_in[20];
  const float* sa  = (const float*)d_in[21]; const float* sb  = (const float*)d_in[22];
  const float* mw2 = (const float*)d_in[23]; const float* mb2 = (const float*)d_in[24];

  float* wsf = (float*)d_ws;
  const size_t A = (size_t)NROWS * 1024; // N*D*8 floats
  float* qbuf = wsf;          // A
  float* kbuf = wsf + A;      // A
  float* nm1  = wsf + 2 * A;  // N
  float* nm2  = nm1 + NROWS;  // N
  float* nm4  = nm2 + NROWS;  // N
  float* vout = (float*)d_out; // used as v / gp-hi / h-hi scratch, final output

  // 1. nm1 = mean multivector norm of src rows
  norms_kernel<<<NROWS, 256, 0, stream>>>(src, nm1);
  // 2-4. q,k,v = mv_linear(LN1(src))
  mvlin_kernel<128, 128, true, false><<<NROWS / 4, 256, 0, stream>>>(
      src, nullptr, wq, bq, ln1_a, nm1, nullptr, nullptr, nullptr, qbuf, nullptr);
  mvlin_kernel<128, 128, true, false><<<NROWS / 4, 256, 0, stream>>>(
      src, nullptr, wk, bk, ln1_a, nm1, nullptr, nullptr, nullptr, kbuf, nullptr);
  mvlin_kernel<128, 128, true, false><<<NROWS / 4, 256, 0, stream>>>(
      src, nullptr, wv, bv, ln1_a, nm1, nullptr, nullptr, nullptr, vout, nullptr);
  // 5. attention, o overwrites q
  attn_kernel<<<(NROWS / SEQL) * NHEAD, 256, 0, stream>>>(qbuf, kbuf, vout);
  // 6. xres = src + mv_linear(o, wo, bo) -> kbuf; nm2
  attnout_kernel<<<NROWS / 4, 256, 0, stream>>>(qbuf, wo, bo, src, kbuf, nm2);
  // 7. gp = GP(mv_linear(LN2(xres),gw1), mv_linear(LN2(xres),gw2)) -> qbuf(lo)+vout(hi)
  gp_kernel<<<NROWS / 4, 256, 0, stream>>>(kbuf, nm2, ln2_a, gw1, gb1, gw2, gb2, qbuf, vout);
  // 8. x3 = LN2(xres) + LN(mv_linear(gp,gw3,gb3), gna) -> kbuf (in place); nm4
  glx3_kernel<<<NROWS / 4, 256, 0, stream>>>(qbuf, vout, gw3, gb3, gna, ln2_a, nm2, kbuf, nm4);
  // 9. h = mv_linear(LN3(x3), mw1, mb1) -> qbuf(lo)+vout(hi)
  mvlin_kernel<128, 256, true, false><<<NROWS / 4, 256, 0, stream>>>(
      kbuf, nullptr, mw1, mb1, ln3_a, nm4, nullptr, nullptr, nullptr, qbuf, vout);
  // 10. MVSiLU in place on both halves
  silu_kernel<<<(NROWS * 128) / 256, 256, 0, stream>>>(qbuf, sa, sb);
  silu_kernel<<<(NROWS * 128) / 256, 256, 0, stream>>>(vout, sa + 512, sb + 512);
  // 11. out = LN3(x3) + mv_linear(h2, mw2, mb2) -> d_out (in-place-safe per block)
  mvlin_kernel<256, 128, false, true><<<NROWS / 4, 256, 0, stream>>>(
      qbuf, vout, mw2, mb2, nullptr, nullptr, kbuf, ln3_a, nm4, vout, nullptr);
}

// Round 2
// 957.297 us; speedup vs baseline: 6.2167x; 6.2167x over previous
//
#include <hip/hip_runtime.h>
#include <hip/hip_bf16.h>
#include <math.h>

#define NROWS 25600
#define SEQL  25
#define EPSV  1e-6f

typedef __hip_bfloat16 bf16;
typedef __attribute__((ext_vector_type(4))) float f32x4;
typedef __attribute__((ext_vector_type(8))) short bf16x8;
typedef unsigned int u32;

#define GLD16(gp_, lp_) __builtin_amdgcn_global_load_lds( \
    (const __attribute__((address_space(1))) u32*)(gp_), \
    (__attribute__((address_space(3))) u32*)(lp_), 16, 0, 0)

// ---------------- Cl(3,0) geometric product (fp32, verified round 0) --------
__device__ __forceinline__ void gprod(const float* a, const float* b, float* r) {
  const int M[8] = {0,1,2,4,3,5,6,7};
  const int P[8] = {0,1,2,4,3,5,6,7};
#pragma unroll
  for (int i = 0; i < 8; ++i) {
    const int ma = M[i];
#pragma unroll
    for (int k = 0; k < 8; ++k) {
      const int mb = M[k];
      int par = 0;
      for (int t = ma >> 1; t; t >>= 1) par += __popc(t & mb);
      const float s = (par & 1) ? -1.f : 1.f;
      r[P[ma ^ mb]] += s * a[i] * b[k];
    }
  }
}

// ---------------- MFMA GEMM: one 128x128 output tile per block --------------
// A planar [8][NROWS][KT] bf16 ; W [4 grades][ON][KT] bf16 (LN fold applied)
// Y planar [8][NROWS][ON] bf16 ; y = acc*invnm[n] + bias[col] (bias plane 0)
// grid: (NROWS/128, ON/128, 8)
template<int KT, int ON>
__global__ __launch_bounds__(256) void gemm_kernel(
    const bf16* __restrict__ A, const bf16* __restrict__ W,
    const float* __restrict__ bias, const float* __restrict__ invnm,
    bf16* __restrict__ Y)
{
  __shared__ __align__(16) short As[128 * 128];
  __shared__ __align__(16) short Bs[128 * 128];
  const int tid  = threadIdx.x;
  const int lane = tid & 63;
  const int wid  = tid >> 6;
  const int pl   = blockIdx.z;
  const int g    = (pl == 0) ? 0 : ((pl < 4) ? 1 : ((pl < 7) ? 2 : 3));
  const size_t n0 = (size_t)blockIdx.x * 128;
  const int c0    = blockIdx.y * 128;
  const bf16* Ab = A + (size_t)pl * NROWS * KT + n0 * KT;
  const bf16* Wb = W + ((size_t)g * ON + c0) * KT;

  f32x4 acc[4][4];
#pragma unroll
  for (int i = 0; i < 4; ++i)
#pragma unroll
    for (int j = 0; j < 4; ++j) acc[i][j] = (f32x4){0.f, 0.f, 0.f, 0.f};

  const int wm = (wid & 1) * 64;
  const int wn = (wid >> 1) * 64;
  const int srow = wid * 32 + (lane >> 4); // +j*4 per staging step
  const int scol = (lane & 15) * 8;

  constexpr int NC = KT / 128;
#pragma unroll
  for (int kc = 0; kc < NC; ++kc) {
#pragma unroll
    for (int j = 0; j < 8; ++j) {
      const bf16* ga = Ab + (size_t)(srow + j * 4) * KT + kc * 128 + scol;
      const bf16* gb = Wb + (size_t)(srow + j * 4) * KT + kc * 128 + scol;
      GLD16(ga, &As[wid * 4096 + j * 512]);
      GLD16(gb, &Bs[wid * 4096 + j * 512]);
    }
    __syncthreads();
#pragma unroll
    for (int ks = 0; ks < 4; ++ks) {
      bf16x8 af[4], bg[4];
#pragma unroll
      for (int i = 0; i < 4; ++i) {
        af[i] = *(const bf16x8*)&As[(wm + i * 16 + (lane & 15)) * 128 + ks * 32 + (lane >> 4) * 8];
        bg[i] = *(const bf16x8*)&Bs[(wn + i * 16 + (lane & 15)) * 128 + ks * 32 + (lane >> 4) * 8];
      }
#pragma unroll
      for (int mi = 0; mi < 4; ++mi)
#pragma unroll
        for (int ni = 0; ni < 4; ++ni)
          acc[mi][ni] = __builtin_amdgcn_mfma_f32_16x16x32_bf16(af[mi], bg[ni], acc[mi][ni], 0, 0, 0);
    }
    if (kc + 1 < NC) __syncthreads();
  }

  const int cr = (lane >> 4) * 4;
  const int cc = lane & 15;
  bf16* Yb = Y + (size_t)pl * NROWS * ON;
#pragma unroll
  for (int mi = 0; mi < 4; ++mi) {
#pragma unroll
    for (int j = 0; j < 4; ++j) {
      const size_t n = n0 + wm + mi * 16 + cr + j;
      const float sc = invnm ? invnm[n] : 1.f;
#pragma unroll
      for (int ni = 0; ni < 4; ++ni) {
        const int colg = c0 + wn + ni * 16 + cc;
        float v = acc[mi][ni][j] * sc;
        if (pl == 0) v += bias[colg];
        Yb[n * ON + colg] = __float2bfloat16(v);
      }
    }
  }
}

// ---------------- weight prep: [O][K][4] f32 -> [4][O][K] bf16 (LN fold) ----
__global__ __launch_bounds__(256) void wprep_kernel(
    const float* __restrict__ w, const float* __restrict__ lnscale,
    bf16* __restrict__ out, int O, int K)
{
  const int idx = blockIdx.x * 256 + threadIdx.x; // o*K + k
  if (idx >= O * K) return;
  const int k = idx % K;
  const float s = lnscale ? lnscale[k] : 1.f;
  const float4 wv = *(const float4*)(w + (size_t)idx * 4);
  const size_t P = (size_t)O * K;
  out[0 * P + idx] = __float2bfloat16(wv.x * s);
  out[1 * P + idx] = __float2bfloat16(wv.y * s);
  out[2 * P + idx] = __float2bfloat16(wv.z * s);
  out[3 * P + idx] = __float2bfloat16(wv.w * s);
}

// ---------------- repack: src f32 [n][128][8] -> Xp bf16 planar + 1/nm1 -----
__global__ __launch_bounds__(256) void repack_kernel(
    const float* __restrict__ src, bf16* __restrict__ Xp, float* __restrict__ nminv)
{
  __shared__ float red[256];
  const int tid = threadIdx.x;
  const size_t n = (size_t)blockIdx.x * 2 + (tid >> 7);
  const int c = tid & 127;
  const size_t P = (size_t)NROWS * 128;
  const size_t idx = n * 128 + c;
  const float* sp = src + idx * 8;
  float v[8];
  const float4 s0 = *(const float4*)sp;
  const float4 s1 = *(const float4*)(sp + 4);
  v[0]=s0.x; v[1]=s0.y; v[2]=s0.z; v[3]=s0.w;
  v[4]=s1.x; v[5]=s1.y; v[6]=s1.z; v[7]=s1.w;
  float ss = 0.f;
#pragma unroll
  for (int p = 0; p < 8; ++p) {
    Xp[p * P + idx] = __float2bfloat16(v[p]);
    ss += v[p] * v[p];
  }
  red[tid] = sqrtf(ss);
  __syncthreads();
  for (int off = 64; off > 0; off >>= 1) {
    if ((tid & 127) < off) red[tid] += red[tid + off];
    __syncthreads();
  }
  if (c == 0) nminv[n] = 1.f / (red[tid] / 128.f + EPSV);
}

// ---------------- attention per (b,h); O overwrites Q in place --------------
__global__ __launch_bounds__(256) void attn_kernel(
    bf16* __restrict__ Q, const bf16* __restrict__ K, const bf16* __restrict__ V)
{
  __shared__ __align__(16) float qs[SEQL * 128];
  __shared__ __align__(16) float ks[SEQL * 128];
  __shared__ __align__(16) float vs[SEQL * 128];
  __shared__ float ss[SEQL][SEQL];
  const int tid = threadIdx.x;
  const int b = blockIdx.x >> 3;
  const int h = blockIdx.x & 7;
  const size_t PS = (size_t)NROWS * 128;

  for (int idx = tid; idx < SEQL * 128; idx += 256) {
    const int s = idx >> 7;
    const int f = idx & 127;
    const int p = f >> 4, d = f & 15;
    const size_t g = (size_t)p * PS + ((size_t)(b * SEQL + s)) * 128 + h * 16 + d;
    qs[idx] = __bfloat162float(Q[g]);
    ks[idx] = __bfloat162float(K[g]);
    vs[idx] = __bfloat162float(V[g]);
  }
  __syncthreads();

  const float scale = 0.08838834764831845f; // 1/sqrt(128)
  for (int p = tid; p < SEQL * SEQL; p += 256) {
    const int s = p / SEQL;
    const int t = p - s * SEQL;
    float acc = 0.f;
    for (int j = 0; j < 128; ++j) acc += qs[s * 128 + j] * ks[t * 128 + j];
    ss[s][t] = acc * scale;
  }
  __syncthreads();

  if (tid < SEQL) {
    float m = -1e30f;
    for (int t = 0; t < SEQL; ++t) m = fmaxf(m, ss[tid][t]);
    float sum = 0.f;
    for (int t = 0; t < SEQL; ++t) { const float e = expf(ss[tid][t] - m); ss[tid][t] = e; sum += e; }
    const float isum = 1.f / sum;
    for (int t = 0; t < SEQL; ++t) ss[tid][t] *= isum;
  }
  __syncthreads();

  for (int idx = tid; idx < SEQL * 128; idx += 256) {
    const int s = idx >> 7;
    const int f = idx & 127;
    const int p = f >> 4, d = f & 15;
    float acc = 0.f;
#pragma unroll
    for (int t = 0; t < SEQL; ++t) acc += ss[s][t] * vs[t * 128 + f];
    Q[(size_t)p * PS + ((size_t)(b * SEQL + s)) * 128 + h * 16 + d] = __float2bfloat16(acc);
  }
}

// ---------------- xres = src + AO ; Xres bf16 planar + 1/nm2 ----------------
__global__ __launch_bounds__(256) void xres_kernel(
    const float* __restrict__ src, const bf16* __restrict__ AO,
    bf16* __restrict__ X, float* __restrict__ nminv)
{
  __shared__ float red[256];
  const int tid = threadIdx.x;
  const size_t n = (size_t)blockIdx.x * 2 + (tid >> 7);
  const int c = tid & 127;
  const size_t P = (size_t)NROWS * 128;
  const size_t idx = n * 128 + c;
  const float* sp = src + idx * 8;
  float v[8];
  const float4 s0 = *(const float4*)sp;
  const float4 s1 = *(const float4*)(sp + 4);
  v[0]=s0.x; v[1]=s0.y; v[2]=s0.z; v[3]=s0.w;
  v[4]=s1.x; v[5]=s1.y; v[6]=s1.z; v[7]=s1.w;
  float ss = 0.f;
#pragma unroll
  for (int p = 0; p < 8; ++p) {
    v[p] += __bfloat162float(AO[p * P + idx]);
    X[p * P + idx] = __float2bfloat16(v[p]);
    ss += v[p] * v[p];
  }
  red[tid] = sqrtf(ss);
  __syncthreads();
  for (int off = 64; off > 0; off >>= 1) {
    if ((tid & 127) < off) red[tid] += red[tid + off];
    __syncthreads();
  }
  if (c == 0) nminv[n] = 1.f / (red[tid] / 128.f + EPSV);
}

// ---------------- norm of a 128-ch planar tensor -> 1/nm --------------------
__global__ __launch_bounds__(256) void normk_kernel(
    const bf16* __restrict__ X, float* __restrict__ nminv)
{
  __shared__ float red[256];
  const int tid = threadIdx.x;
  const size_t n = (size_t)blockIdx.x * 2 + (tid >> 7);
  const int c = tid & 127;
  const size_t P = (size_t)NROWS * 128;
  const size_t idx = n * 128 + c;
  float ss = 0.f;
#pragma unroll
  for (int p = 0; p < 8; ++p) {
    const float v = __bfloat162float(X[p * P + idx]);
    ss += v * v;
  }
  red[tid] = sqrtf(ss);
  __syncthreads();
  for (int off = 64; off > 0; off >>= 1) {
    if ((tid & 127) < off) red[tid] += red[tid + off];
    __syncthreads();
  }
  if (c == 0) nminv[n] = 1.f / (red[tid] / 128.f + EPSV);
}

// ---------------- GP elementwise (in place over XL) -------------------------
__global__ __launch_bounds__(256) void gp_kernel(
    bf16* __restrict__ XL, const bf16* __restrict__ XR)
{
  const size_t idx = (size_t)blockIdx.x * 256 + threadIdx.x; // n*256+c
  const size_t P = (size_t)NROWS * 256;
  float a[8], b[8], r[8] = {0.f,0.f,0.f,0.f,0.f,0.f,0.f,0.f};
#pragma unroll
  for (int p = 0; p < 8; ++p) {
    a[p] = __bfloat162float(XL[p * P + idx]);
    b[p] = __bfloat162float(XR[p * P + idx]);
  }
  gprod(a, b, r);
#pragma unroll
  for (int p = 0; p < 8; ++p) XL[p * P + idx] = __float2bfloat16(r[p]);
}

// ---------------- x3 = ln2a*Xres/nm2 + gna*Gl/nmg (in place) + 1/nm4 --------
__global__ __launch_bounds__(256) void combine_kernel(
    bf16* __restrict__ X, const bf16* __restrict__ Gl,
    const float* __restrict__ ln2a, const float* __restrict__ gna,
    const float* __restrict__ nm2inv, const float* __restrict__ nmginv,
    float* __restrict__ nm4inv)
{
  __shared__ float red[256];
  const int tid = threadIdx.x;
  const size_t n = (size_t)blockIdx.x * 2 + (tid >> 7);
  const int c = tid & 127;
  const size_t P = (size_t)NROWS * 128;
  const size_t idx = n * 128 + c;
  const float s2 = ln2a[c] * nm2inv[n];
  const float sg = gna[c] * nmginv[n];
  float ss = 0.f;
#pragma unroll
  for (int p = 0; p < 8; ++p) {
    const float v = s2 * __bfloat162float(X[p * P + idx])
                  + sg * __bfloat162float(Gl[p * P + idx]);
    X[p * P + idx] = __float2bfloat16(v);
    ss += v * v;
  }
  red[tid] = sqrtf(ss);
  __syncthreads();
  for (int off = 64; off > 0; off >>= 1) {
    if ((tid & 127) < off) red[tid] += red[tid + off];
    __syncthreads();
  }
  if (c == 0) nm4inv[n] = 1.f / (red[tid] / 128.f + EPSV);
}

// ---------------- MVSiLU in place on 256-ch planar tensor -------------------
__global__ __launch_bounds__(256) void silu_kernel(
    bf16* __restrict__ H, const float* __restrict__ sa, const float* __restrict__ sb)
{
  const size_t idx = (size_t)blockIdx.x * 256 + threadIdx.x; // n*256+c
  const int c = (int)(idx & 255);
  const size_t P = (size_t)NROWS * 256;
  float v[8];
#pragma unroll
  for (int p = 0; p < 8; ++p) v[p] = __bfloat162float(H[p * P + idx]);
  const float i0 = v[0];
  const float i1 = v[1]*v[1] + v[2]*v[2] + v[3]*v[3];
  const float i2 = v[4]*v[4] + v[5]*v[5] + v[6]*v[6];
  const float i3 = v[7]*v[7];
  const float g0 = 1.f / (1.f + expf(-(sa[c*4+0]*i0 + sb[c*4+0])));
  const float g1 = 1.f / (1.f + expf(-(sa[c*4+1]*i1 + sb[c*4+1])));
  const float g2 = 1.f / (1.f + expf(-(sa[c*4+2]*i2 + sb[c*4+2])));
  const float g3 = 1.f / (1.f + expf(-(sa[c*4+3]*i3 + sb[c*4+3])));
  v[0]*=g0; v[1]*=g1; v[2]*=g1; v[3]*=g1; v[4]*=g2; v[5]*=g2; v[6]*=g2; v[7]*=g3;
#pragma unroll
  for (int p = 0; p < 8; ++p) H[p * P + idx] = __float2bfloat16(v[p]);
}

// ---------------- final: out = ln3a*X3/nm4 + FF (fp32 interleaved) ----------
__global__ __launch_bounds__(256) void final_kernel(
    const bf16* __restrict__ X3, const bf16* __restrict__ FF,
    const float* __restrict__ ln3a, const float* __restrict__ nm4inv,
    float* __restrict__ out)
{
  const size_t idx = (size_t)blockIdx.x * 256 + threadIdx.x; // n*128+c
  const int c = (int)(idx & 127);
  const size_t n = idx >> 7;
  const size_t P = (size_t)NROWS * 128;
  const float s = ln3a[c] * nm4inv[n];
  float o[8];
#pragma unroll
  for (int p = 0; p < 8; ++p)
    o[p] = s * __bfloat162float(X3[p * P + idx]) + __bfloat162float(FF[p * P + idx]);
  float4 lo, hi;
  lo.x=o[0]; lo.y=o[1]; lo.z=o[2]; lo.w=o[3];
  hi.x=o[4]; hi.y=o[5]; hi.z=o[6]; hi.w=o[7];
  *reinterpret_cast<float4*>(out + idx * 8)     = lo;
  *reinterpret_cast<float4*>(out + idx * 8 + 4) = hi;
}

// ---------------- launch ----------------------------------------------------
extern "C" void kernel_launch(void* const* d_in, const int* in_sizes, int n_in,
                              void* d_out, int out_size, void* d_ws, size_t ws_size,
                              hipStream_t stream) {
  (void)in_sizes; (void)n_in; (void)out_size; (void)ws_size;
  const float* src   = (const float*)d_in[0];
  const float* ln1_a = (const float*)d_in[1];
  const float* ln2_a = (const float*)d_in[2];
  const float* ln3_a = (const float*)d_in[3];
  const float* wq = (const float*)d_in[4];  const float* bq = (const float*)d_in[5];
  const float* wk = (const float*)d_in[6];  const float* bk = (const float*)d_in[7];
  const float* wv = (const float*)d_in[8];  const float* bv = (const float*)d_in[9];
  const float* wo = (const float*)d_in[10]; const float* bo = (const float*)d_in[11];
  const float* gw1 = (const float*)d_in[12]; const float* gb1 = (const float*)d_in[13];
  const float* gw2 = (const float*)d_in[14]; const float* gb2 = (const float*)d_in[15];
  const float* gw3 = (const float*)d_in[16]; const float* gb3 = (const float*)d_in[17];
  const float* gna = (const float*)d_in[18];
  const float* mw1 = (const float*)d_in[19]; const float* mb1 = (const float*)d_in[20];
  const float* sa  = (const float*)d_in[21]; const float* sb  = (const float*)d_in[22];
  const float* mw2 = (const float*)d_in[23]; const float* mb2 = (const float*)d_in[24];

  const size_t P128 = (size_t)NROWS * 128; // elems per 128-ch plane
  char* ws = (char*)d_ws;
  bf16* R1 = (bf16*)ws;                       // 104,857,600 B (P256 capable)
  bf16* R2 = (bf16*)(ws + 104857600);         //  52,428,800 B (P128)
  bf16* WQ = (bf16*)(ws + 157286400);         // weight planes (bf16)
  bf16* WK = WQ + 65536;
  bf16* WV = WK + 65536;
  bf16* WO = WV + 65536;
  bf16* WG1 = WO + 65536;
  bf16* WG2 = WG1 + 131072;
  bf16* WG3 = WG2 + 131072;
  bf16* WM1 = WG3 + 131072;
  bf16* WM2 = WM1 + 131072;
  float* nm1 = (float*)(ws + 159121408);
  float* nm2 = nm1 + NROWS;
  float* nmg = nm2 + NROWS;
  float* nm4 = nmg + NROWS;

  bf16* Dd = (bf16*)d_out;  // 52,428,800 bf16 elems: Q/O -> XL/GP -> H
  bf16* Xp = R2;            // bf16 planar src, later Xres/X3 (in place)
  bf16* Kp = R1;            // K planes, later AO / Gl
  bf16* Vp = R1 + P128;     // V planes, later FF

  // weight prep (LN scales folded where input is layernormed)
  wprep_kernel<<<64, 256, 0, stream>>>(wq, ln1_a, WQ, 128, 128);
  wprep_kernel<<<64, 256, 0, stream>>>(wk, ln1_a, WK, 128, 128);
  wprep_kernel<<<64, 256, 0, stream>>>(wv, ln1_a, WV, 128, 128);
  wprep_kernel<<<64, 256, 0, stream>>>(wo, nullptr, WO, 128, 128);
  wprep_kernel<<<128, 256, 0, stream>>>(gw1, ln2_a, WG1, 256, 128);
  wprep_kernel<<<128, 256, 0, stream>>>(gw2, ln2_a, WG2, 256, 128);
  wprep_kernel<<<128, 256, 0, stream>>>(gw3, nullptr, WG3, 128, 256);
  wprep_kernel<<<128, 256, 0, stream>>>(mw1, ln3_a, WM1, 256, 128);
  wprep_kernel<<<128, 256, 0, stream>>>(mw2, nullptr, WM2, 128, 256);

  // 1. repack src -> Xp (bf16 planar) + 1/nm1
  repack_kernel<<<NROWS / 2, 256, 0, stream>>>(src, Xp, nm1);

  // 2. Q,K,V GEMMs (LN1 folded)
  dim3 g128(NROWS / 128, 1, 8), g256(NROWS / 128, 2, 8);
  gemm_kernel<128, 128><<<g128, 256, 0, stream>>>(Xp, WQ, bq, nm1, Dd);
  gemm_kernel<128, 128><<<g128, 256, 0, stream>>>(Xp, WK, bk, nm1, Kp);
  gemm_kernel<128, 128><<<g128, 256, 0, stream>>>(Xp, WV, bv, nm1, Vp);

  // 3. attention (O overwrites Q planes in Dd)
  attn_kernel<<<(NROWS / SEQL) * 8, 256, 0, stream>>>(Dd, Kp, Vp);

  // 4. AO = mv_linear(O, wo, bo) -> R1 (K planes dead)
  gemm_kernel<128, 128><<<g128, 256, 0, stream>>>(Dd, WO, bo, nullptr, Kp);

  // 5. Xres = src + AO -> R2 (Xp dead) ; 1/nm2
  xres_kernel<<<NROWS / 2, 256, 0, stream>>>(src, Kp, Xp, nm2);

  // 6. XL/XR = mv_linear(LN2(Xres), gw1/gw2) ; XL -> Dd, XR -> R1 (full)
  gemm_kernel<128, 256><<<g256, 256, 0, stream>>>(Xp, WG1, gb1, nm2, Dd);
  gemm_kernel<128, 256><<<g256, 256, 0, stream>>>(Xp, WG2, gb2, nm2, R1);

  // 7. GP in place over XL
  gp_kernel<<<NROWS, 256, 0, stream>>>(Dd, R1);

  // 8. Gl = mv_linear(GP, gw3, gb3) -> R1 first half ; 1/nmg
  gemm_kernel<256, 128><<<g128, 256, 0, stream>>>(Dd, WG3, gb3, nullptr, Kp);
  normk_kernel<<<NROWS / 2, 256, 0, stream>>>(Kp, nmg);

  // 9. X3 = ln2a*Xres/nm2 + gna*Gl/nmg (in place in R2) ; 1/nm4
  combine_kernel<<<NROWS / 2, 256, 0, stream>>>(Xp, Kp, ln2_a, gna, nm2, nmg, nm4);

  // 10. H = mv_linear(LN3(X3), mw1, mb1) -> Dd (GP dead)
  gemm_kernel<128, 256><<<g256, 256, 0, stream>>>(Xp, WM1, mb1, nm4, Dd);

  // 11. MVSiLU in place on H
  silu_kernel<<<NROWS, 256, 0, stream>>>(Dd, sa, sb);

  // 12. FF = mv_linear(H, mw2, mb2) -> R1 second half (Vp slot)
  gemm_kernel<256, 128><<<g128, 256, 0, stream>>>(Dd, WM2, mb2, nullptr, Vp);

  // 13. out = ln3a*X3/nm4 + FF -> d_out fp32 interleaved
  final_kernel<<<(NROWS * 128) / 256, 256, 0, stream>>>(Xp, Vp, ln3_a, nm4, (float*)d_out);
}

// Round 3
// 681.238 us; speedup vs baseline: 8.7359x; 1.4052x over previous
//
#include <hip/hip_runtime.h>
#include <hip/hip_bf16.h>
#include <math.h>

#define NROWS 25600
#define SEQL  25
#define EPSV  1e-6f

typedef __hip_bfloat16 bf16;
typedef __attribute__((ext_vector_type(4))) float f32x4;
typedef __attribute__((ext_vector_type(8))) short bf16x8;
typedef unsigned int u32;

#define GLD16(gp_, lp_) __builtin_amdgcn_global_load_lds( \
    (const __attribute__((address_space(1))) u32*)(gp_), \
    (__attribute__((address_space(3))) u32*)(lp_), 16, 0, 0)

// ---------------- Cl(3,0) geometric product (fp32, verified round 0) --------
__device__ __forceinline__ void gprod(const float* a, const float* b, float* r) {
  const int M[8] = {0,1,2,4,3,5,6,7};
  const int P[8] = {0,1,2,4,3,5,6,7};
#pragma unroll
  for (int i = 0; i < 8; ++i) {
    const int ma = M[i];
#pragma unroll
    for (int k = 0; k < 8; ++k) {
      const int mb = M[k];
      int par = 0;
      for (int t = ma >> 1; t; t >>= 1) par += __popc(t & mb);
      const float s = (par & 1) ? -1.f : 1.f;
      r[P[ma ^ mb]] += s * a[i] * b[k];
    }
  }
}

// ---------------- MFMA GEMM: one 128x128 output tile per block --------------
// A planar [8][NROWS][KT] bf16 ; W [4 grades][ON][KT] bf16 (LN fold applied)
// Y planar [8][NROWS][ON] bf16 ; y = acc*invnm[n] + bias[col] (bias plane 0)
// grid: (NROWS/128, ON/128, 8)
template<int KT, int ON>
__global__ __launch_bounds__(256) void gemm_kernel(
    const bf16* __restrict__ A, const bf16* __restrict__ W,
    const float* __restrict__ bias, const float* __restrict__ invnm,
    bf16* __restrict__ Y)
{
  __shared__ __align__(16) short As[128 * 128];
  __shared__ __align__(16) short Bs[128 * 128];
  const int tid  = threadIdx.x;
  const int lane = tid & 63;
  const int wid  = tid >> 6;
  const int pl   = blockIdx.z;
  const int g    = (pl == 0) ? 0 : ((pl < 4) ? 1 : ((pl < 7) ? 2 : 3));
  const size_t n0 = (size_t)blockIdx.x * 128;
  const int c0    = blockIdx.y * 128;
  const bf16* Ab = A + (size_t)pl * NROWS * KT + n0 * KT;
  const bf16* Wb = W + ((size_t)g * ON + c0) * KT;

  f32x4 acc[4][4];
#pragma unroll
  for (int i = 0; i < 4; ++i)
#pragma unroll
    for (int j = 0; j < 4; ++j) acc[i][j] = (f32x4){0.f, 0.f, 0.f, 0.f};

  const int wm = (wid & 1) * 64;
  const int wn = (wid >> 1) * 64;
  const int srow = wid * 32 + (lane >> 4);
  const int scol = (lane & 15) * 8;

  constexpr int NC = KT / 128;
#pragma unroll
  for (int kc = 0; kc < NC; ++kc) {
#pragma unroll
    for (int j = 0; j < 8; ++j) {
      const bf16* ga = Ab + (size_t)(srow + j * 4) * KT + kc * 128 + scol;
      const bf16* gb = Wb + (size_t)(srow + j * 4) * KT + kc * 128 + scol;
      GLD16(ga, &As[wid * 4096 + j * 512]);
      GLD16(gb, &Bs[wid * 4096 + j * 512]);
    }
    __syncthreads();
#pragma unroll
    for (int ks = 0; ks < 4; ++ks) {
      bf16x8 af[4], bg[4];
#pragma unroll
      for (int i = 0; i < 4; ++i) {
        af[i] = *(const bf16x8*)&As[(wm + i * 16 + (lane & 15)) * 128 + ks * 32 + (lane >> 4) * 8];
        bg[i] = *(const bf16x8*)&Bs[(wn + i * 16 + (lane & 15)) * 128 + ks * 32 + (lane >> 4) * 8];
      }
#pragma unroll
      for (int mi = 0; mi < 4; ++mi)
#pragma unroll
        for (int ni = 0; ni < 4; ++ni)
          acc[mi][ni] = __builtin_amdgcn_mfma_f32_16x16x32_bf16(af[mi], bg[ni], acc[mi][ni], 0, 0, 0);
    }
    if (kc + 1 < NC) __syncthreads();
  }

  const int cr = (lane >> 4) * 4;
  const int cc = lane & 15;
  bf16* Yb = Y + (size_t)pl * NROWS * ON;
#pragma unroll
  for (int mi = 0; mi < 4; ++mi) {
#pragma unroll
    for (int j = 0; j < 4; ++j) {
      const size_t n = n0 + wm + mi * 16 + cr + j;
      const float sc = invnm ? invnm[n] : 1.f;
#pragma unroll
      for (int ni = 0; ni < 4; ++ni) {
        const int colg = c0 + wn + ni * 16 + cc;
        float v = acc[mi][ni][j] * sc;
        if (pl == 0) v += bias[colg];
        Yb[n * ON + colg] = __float2bfloat16(v);
      }
    }
  }
}

// ---------------- weight prep: [O][K][4] f32 -> [4][O][K] bf16 (LN fold) ----
__global__ __launch_bounds__(256) void wprep_kernel(
    const float* __restrict__ w, const float* __restrict__ lnscale,
    bf16* __restrict__ out, int O, int K)
{
  const int idx = blockIdx.x * 256 + threadIdx.x;
  if (idx >= O * K) return;
  const int k = idx % K;
  const float s = lnscale ? lnscale[k] : 1.f;
  const float4 wv = *(const float4*)(w + (size_t)idx * 4);
  const size_t P = (size_t)O * K;
  out[0 * P + idx] = __float2bfloat16(wv.x * s);
  out[1 * P + idx] = __float2bfloat16(wv.y * s);
  out[2 * P + idx] = __float2bfloat16(wv.z * s);
  out[3 * P + idx] = __float2bfloat16(wv.w * s);
}

// ---------------- repack: src f32 [n][128][8] -> Xp bf16 planar + 1/nm1 -----
__global__ __launch_bounds__(256) void repack_kernel(
    const float* __restrict__ src, bf16* __restrict__ Xp, float* __restrict__ nminv)
{
  __shared__ float red[256];
  const int tid = threadIdx.x;
  const size_t n = (size_t)blockIdx.x * 2 + (tid >> 7);
  const int c = tid & 127;
  const size_t P = (size_t)NROWS * 128;
  const size_t idx = n * 128 + c;
  const float* sp = src + idx * 8;
  float v[8];
  const float4 s0 = *(const float4*)sp;
  const float4 s1 = *(const float4*)(sp + 4);
  v[0]=s0.x; v[1]=s0.y; v[2]=s0.z; v[3]=s0.w;
  v[4]=s1.x; v[5]=s1.y; v[6]=s1.z; v[7]=s1.w;
  float ss = 0.f;
#pragma unroll
  for (int p = 0; p < 8; ++p) {
    Xp[p * P + idx] = __float2bfloat16(v[p]);
    ss += v[p] * v[p];
  }
  red[tid] = sqrtf(ss);
  __syncthreads();
  for (int off = 64; off > 0; off >>= 1) {
    if ((tid & 127) < off) red[tid] += red[tid + off];
    __syncthreads();
  }
  if (c == 0) nminv[n] = 1.f / (red[tid] / 128.f + EPSV);
}

// ---------------- attention: 1 wave per (b,h); MFMA QK^T, in-reg softmax ----
// O overwrites Q in place. Block = 4 waves = 4 head-jobs.
__global__ __launch_bounds__(256) void attn_kernel(
    bf16* __restrict__ Q, const bf16* __restrict__ K, const bf16* __restrict__ V)
{
  __shared__ float Pld[4][32 * 36]; // per-wave P, stride 36 f32 (16B-aligned rows)
  const int tid  = threadIdx.x;
  const int lane = tid & 63;
  const int wid  = tid >> 6;
  const int job  = blockIdx.x * 4 + wid;
  const int b    = job >> 3;
  const int h    = job & 7;
  const size_t PS = (size_t)NROWS * 128;
  const int rowbase = b * SEQL;
  const int l15 = lane & 15;
  const int lg  = lane >> 4; // 0..3

  // ---- QK^T: 2x2 tiles of 16x16, k=128 in 4 steps ----
  f32x4 acc[2][2];
#pragma unroll
  for (int si = 0; si < 2; ++si)
#pragma unroll
    for (int ti = 0; ti < 2; ++ti) acc[si][ti] = (f32x4){0.f,0.f,0.f,0.f};

#pragma unroll
  for (int ks = 0; ks < 4; ++ks) {
    const int f = ks * 32 + lg * 8;
    const int p = f >> 4, d = f & 15;
    bf16x8 aq[2], bk[2];
#pragma unroll
    for (int si = 0; si < 2; ++si) {
      int s = si * 16 + l15; if (s > 24) s = 24; // clamp pad rows
      aq[si] = *(const bf16x8*)(Q + (size_t)p * PS + (size_t)(rowbase + s) * 128 + h * 16 + d);
    }
#pragma unroll
    for (int ti = 0; ti < 2; ++ti) {
      int t = ti * 16 + l15; if (t > 24) t = 24;
      bk[ti] = *(const bf16x8*)(K + (size_t)p * PS + (size_t)(rowbase + t) * 128 + h * 16 + d);
    }
#pragma unroll
    for (int si = 0; si < 2; ++si)
#pragma unroll
      for (int ti = 0; ti < 2; ++ti)
        acc[si][ti] = __builtin_amdgcn_mfma_f32_16x16x32_bf16(aq[si], bk[ti], acc[si][ti], 0, 0, 0);
  }

  // ---- scale + mask + in-register softmax over t (cols, 16-lane groups) ----
  const float scale = 0.08838834764831845f; // 1/sqrt(128)
  float pv[2][2][4];
#pragma unroll
  for (int si = 0; si < 2; ++si)
#pragma unroll
    for (int ti = 0; ti < 2; ++ti)
#pragma unroll
      for (int r = 0; r < 4; ++r) {
        float v = acc[si][ti][r] * scale;
        if (ti * 16 + l15 > 24) v = -1e30f;
        pv[si][ti][r] = v;
      }
#pragma unroll
  for (int si = 0; si < 2; ++si)
#pragma unroll
    for (int r = 0; r < 4; ++r) {
      float m = fmaxf(pv[si][0][r], pv[si][1][r]);
#pragma unroll
      for (int off = 1; off < 16; off <<= 1) m = fmaxf(m, __shfl_xor(m, off));
      const float e0 = __expf(pv[si][0][r] - m);
      const float e1 = __expf(pv[si][1][r] - m);
      float sum = e0 + e1;
#pragma unroll
      for (int off = 1; off < 16; off <<= 1) sum += __shfl_xor(sum, off);
      const float inv = 1.f / sum;
      pv[si][0][r] = e0 * inv;
      pv[si][1][r] = e1 * inv;
    }

  // ---- write P to LDS: row s = si*16+lg*4+r, col t = ti*16+l15 ----
  float* Pw = &Pld[wid][0];
#pragma unroll
  for (int si = 0; si < 2; ++si)
#pragma unroll
    for (int ti = 0; ti < 2; ++ti)
#pragma unroll
      for (int r = 0; r < 4; ++r)
        Pw[(si * 16 + lg * 4 + r) * 36 + ti * 16 + l15] = pv[si][ti][r];
  __syncthreads();

  // ---- PV: each lane owns f-pair f0 = 2*lane; V rows in registers ----
  const int p2 = lane >> 3;           // f0>>4
  const int d2 = (lane & 7) * 2;      // f0&15
  const bf16* vb = V + (size_t)p2 * PS + (size_t)rowbase * 128 + h * 16 + d2;
  float vlo[32], vhi[32];
#pragma unroll
  for (int t = 0; t < SEQL; ++t) {
    const __hip_bfloat162 vv = *(const __hip_bfloat162*)(vb + (size_t)t * 128);
    vlo[t] = __bfloat162float(vv.x);
    vhi[t] = __bfloat162float(vv.y);
  }
#pragma unroll
  for (int t = SEQL; t < 32; ++t) { vlo[t] = 0.f; vhi[t] = 0.f; }

  bf16* ob = Q + (size_t)p2 * PS + (size_t)rowbase * 128 + h * 16 + d2;
  for (int s = 0; s < SEQL; ++s) {
    const float4* pr = reinterpret_cast<const float4*>(&Pld[wid][s * 36]);
    float a0 = 0.f, a1 = 0.f;
#pragma unroll
    for (int t4 = 0; t4 < 8; ++t4) {
      const float4 pq = pr[t4];
      a0 += pq.x * vlo[t4*4+0] + pq.y * vlo[t4*4+1] + pq.z * vlo[t4*4+2] + pq.w * vlo[t4*4+3];
      a1 += pq.x * vhi[t4*4+0] + pq.y * vhi[t4*4+1] + pq.z * vhi[t4*4+2] + pq.w * vhi[t4*4+3];
    }
    __hip_bfloat162 o2;
    o2.x = __float2bfloat16(a0);
    o2.y = __float2bfloat16(a1);
    *(__hip_bfloat162*)(ob + (size_t)s * 128) = o2;
  }
}

// ---------------- xres = src + AO ; Xres bf16 planar + 1/nm2 ----------------
__global__ __launch_bounds__(256) void xres_kernel(
    const float* __restrict__ src, const bf16* __restrict__ AO,
    bf16* __restrict__ X, float* __restrict__ nminv)
{
  __shared__ float red[256];
  const int tid = threadIdx.x;
  const size_t n = (size_t)blockIdx.x * 2 + (tid >> 7);
  const int c = tid & 127;
  const size_t P = (size_t)NROWS * 128;
  const size_t idx = n * 128 + c;
  const float* sp = src + idx * 8;
  float v[8];
  const float4 s0 = *(const float4*)sp;
  const float4 s1 = *(const float4*)(sp + 4);
  v[0]=s0.x; v[1]=s0.y; v[2]=s0.z; v[3]=s0.w;
  v[4]=s1.x; v[5]=s1.y; v[6]=s1.z; v[7]=s1.w;
  float ss = 0.f;
#pragma unroll
  for (int p = 0; p < 8; ++p) {
    v[p] += __bfloat162float(AO[p * P + idx]);
    X[p * P + idx] = __float2bfloat16(v[p]);
    ss += v[p] * v[p];
  }
  red[tid] = sqrtf(ss);
  __syncthreads();
  for (int off = 64; off > 0; off >>= 1) {
    if ((tid & 127) < off) red[tid] += red[tid + off];
    __syncthreads();
  }
  if (c == 0) nminv[n] = 1.f / (red[tid] / 128.f + EPSV);
}

// ---------------- GP elementwise (in place over XL) -------------------------
__global__ __launch_bounds__(256) void gp_kernel(
    bf16* __restrict__ XL, const bf16* __restrict__ XR)
{
  const size_t idx = (size_t)blockIdx.x * 256 + threadIdx.x;
  const size_t P = (size_t)NROWS * 256;
  float a[8], b[8], r[8] = {0.f,0.f,0.f,0.f,0.f,0.f,0.f,0.f};
#pragma unroll
  for (int p = 0; p < 8; ++p) {
    a[p] = __bfloat162float(XL[p * P + idx]);
    b[p] = __bfloat162float(XR[p * P + idx]);
  }
  gprod(a, b, r);
#pragma unroll
  for (int p = 0; p < 8; ++p) XL[p * P + idx] = __float2bfloat16(r[p]);
}

// ---- x3 = ln2a*Xres/nm2 + gna*Gl/nmg (nmg computed in-kernel); 1/nm4 -------
__global__ __launch_bounds__(256) void combine_kernel(
    bf16* __restrict__ X, const bf16* __restrict__ Gl,
    const float* __restrict__ ln2a, const float* __restrict__ gna,
    const float* __restrict__ nm2inv, float* __restrict__ nm4inv)
{
  __shared__ float red[256];
  const int tid = threadIdx.x;
  const size_t n = (size_t)blockIdx.x * 2 + (tid >> 7);
  const int c = tid & 127;
  const size_t P = (size_t)NROWS * 128;
  const size_t idx = n * 128 + c;

  // phase 1: row norm of Gl
  float gv[8];
  float ssg = 0.f;
#pragma unroll
  for (int p = 0; p < 8; ++p) {
    gv[p] = __bfloat162float(Gl[p * P + idx]);
    ssg += gv[p] * gv[p];
  }
  red[tid] = sqrtf(ssg);
  __syncthreads();
  for (int off = 64; off > 0; off >>= 1) {
    if ((tid & 127) < off) red[tid] += red[tid + off];
    __syncthreads();
  }
  const float invg = 1.f / (red[tid & 128] / 128.f + EPSV);
  __syncthreads();

  // phase 2: combine + row norm of result
  const float s2 = ln2a[c] * nm2inv[n];
  const float sg = gna[c] * invg;
  float ss = 0.f;
#pragma unroll
  for (int p = 0; p < 8; ++p) {
    const float v = s2 * __bfloat162float(X[p * P + idx]) + sg * gv[p];
    X[p * P + idx] = __float2bfloat16(v);
    ss += v * v;
  }
  red[tid] = sqrtf(ss);
  __syncthreads();
  for (int off = 64; off > 0; off >>= 1) {
    if ((tid & 127) < off) red[tid] += red[tid + off];
    __syncthreads();
  }
  if (c == 0) nm4inv[n] = 1.f / (red[tid] / 128.f + EPSV);
}

// ---------------- MVSiLU in place on 256-ch planar tensor -------------------
__global__ __launch_bounds__(256) void silu_kernel(
    bf16* __restrict__ H, const float* __restrict__ sa, const float* __restrict__ sb)
{
  const size_t idx = (size_t)blockIdx.x * 256 + threadIdx.x;
  const int c = (int)(idx & 255);
  const size_t P = (size_t)NROWS * 256;
  float v[8];
#pragma unroll
  for (int p = 0; p < 8; ++p) v[p] = __bfloat162float(H[p * P + idx]);
  const float i0 = v[0];
  const float i1 = v[1]*v[1] + v[2]*v[2] + v[3]*v[3];
  const float i2 = v[4]*v[4] + v[5]*v[5] + v[6]*v[6];
  const float i3 = v[7]*v[7];
  const float g0 = 1.f / (1.f + expf(-(sa[c*4+0]*i0 + sb[c*4+0])));
  const float g1 = 1.f / (1.f + expf(-(sa[c*4+1]*i1 + sb[c*4+1])));
  const float g2 = 1.f / (1.f + expf(-(sa[c*4+2]*i2 + sb[c*4+2])));
  const float g3 = 1.f / (1.f + expf(-(sa[c*4+3]*i3 + sb[c*4+3])));
  v[0]*=g0; v[1]*=g1; v[2]*=g1; v[3]*=g1; v[4]*=g2; v[5]*=g2; v[6]*=g2; v[7]*=g3;
#pragma unroll
  for (int p = 0; p < 8; ++p) H[p * P + idx] = __float2bfloat16(v[p]);
}

// ---------------- final: out = ln3a*X3/nm4 + FF (fp32 interleaved) ----------
__global__ __launch_bounds__(256) void final_kernel(
    const bf16* __restrict__ X3, const bf16* __restrict__ FF,
    const float* __restrict__ ln3a, const float* __restrict__ nm4inv,
    float* __restrict__ out)
{
  const size_t idx = (size_t)blockIdx.x * 256 + threadIdx.x;
  const int c = (int)(idx & 127);
  const size_t n = idx >> 7;
  const size_t P = (size_t)NROWS * 128;
  const float s = ln3a[c] * nm4inv[n];
  float o[8];
#pragma unroll
  for (int p = 0; p < 8; ++p)
    o[p] = s * __bfloat162float(X3[p * P + idx]) + __bfloat162float(FF[p * P + idx]);
  float4 lo, hi;
  lo.x=o[0]; lo.y=o[1]; lo.z=o[2]; lo.w=o[3];
  hi.x=o[4]; hi.y=o[5]; hi.z=o[6]; hi.w=o[7];
  *reinterpret_cast<float4*>(out + idx * 8)     = lo;
  *reinterpret_cast<float4*>(out + idx * 8 + 4) = hi;
}

// ---------------- launch ----------------------------------------------------
extern "C" void kernel_launch(void* const* d_in, const int* in_sizes, int n_in,
                              void* d_out, int out_size, void* d_ws, size_t ws_size,
                              hipStream_t stream) {
  (void)in_sizes; (void)n_in; (void)out_size; (void)ws_size;
  const float* src   = (const float*)d_in[0];
  const float* ln1_a = (const float*)d_in[1];
  const float* ln2_a = (const float*)d_in[2];
  const float* ln3_a = (const float*)d_in[3];
  const float* wq = (const float*)d_in[4];  const float* bq = (const float*)d_in[5];
  const float* wk = (const float*)d_in[6];  const float* bk = (const float*)d_in[7];
  const float* wv = (const float*)d_in[8];  const float* bv = (const float*)d_in[9];
  const float* wo = (const float*)d_in[10]; const float* bo = (const float*)d_in[11];
  const float* gw1 = (const float*)d_in[12]; const float* gb1 = (const float*)d_in[13];
  const float* gw2 = (const float*)d_in[14]; const float* gb2 = (const float*)d_in[15];
  const float* gw3 = (const float*)d_in[16]; const float* gb3 = (const float*)d_in[17];
  const float* gna = (const float*)d_in[18];
  const float* mw1 = (const float*)d_in[19]; const float* mb1 = (const float*)d_in[20];
  const float* sa  = (const float*)d_in[21]; const float* sb  = (const float*)d_in[22];
  const float* mw2 = (const float*)d_in[23]; const float* mb2 = (const float*)d_in[24];

  const size_t P128 = (size_t)NROWS * 128;
  char* ws = (char*)d_ws;
  bf16* R1 = (bf16*)ws;                       // 104,857,600 B (P256 capable)
  bf16* R2 = (bf16*)(ws + 104857600);         //  52,428,800 B (P128)
  bf16* WQ = (bf16*)(ws + 157286400);
  bf16* WK = WQ + 65536;
  bf16* WV = WK + 65536;
  bf16* WO = WV + 65536;
  bf16* WG1 = WO + 65536;
  bf16* WG2 = WG1 + 131072;
  bf16* WG3 = WG2 + 131072;
  bf16* WM1 = WG3 + 131072;
  bf16* WM2 = WM1 + 131072;
  float* nm1 = (float*)(ws + 159121408);
  float* nm2 = nm1 + NROWS;
  float* nm4 = nm2 + NROWS;

  bf16* Dd = (bf16*)d_out;
  bf16* Xp = R2;
  bf16* Kp = R1;
  bf16* Vp = R1 + P128;

  wprep_kernel<<<64, 256, 0, stream>>>(wq, ln1_a, WQ, 128, 128);
  wprep_kernel<<<64, 256, 0, stream>>>(wk, ln1_a, WK, 128, 128);
  wprep_kernel<<<64, 256, 0, stream>>>(wv, ln1_a, WV, 128, 128);
  wprep_kernel<<<64, 256, 0, stream>>>(wo, nullptr, WO, 128, 128);
  wprep_kernel<<<128, 256, 0, stream>>>(gw1, ln2_a, WG1, 256, 128);
  wprep_kernel<<<128, 256, 0, stream>>>(gw2, ln2_a, WG2, 256, 128);
  wprep_kernel<<<128, 256, 0, stream>>>(gw3, nullptr, WG3, 128, 256);
  wprep_kernel<<<128, 256, 0, stream>>>(mw1, ln3_a, WM1, 256, 128);
  wprep_kernel<<<128, 256, 0, stream>>>(mw2, nullptr, WM2, 128, 256);

  repack_kernel<<<NROWS / 2, 256, 0, stream>>>(src, Xp, nm1);

  dim3 g128(NROWS / 128, 1, 8), g256(NROWS / 128, 2, 8);
  gemm_kernel<128, 128><<<g128, 256, 0, stream>>>(Xp, WQ, bq, nm1, Dd);
  gemm_kernel<128, 128><<<g128, 256, 0, stream>>>(Xp, WK, bk, nm1, Kp);
  gemm_kernel<128, 128><<<g128, 256, 0, stream>>>(Xp, WV, bv, nm1, Vp);

  // attention: 1 wave per (b,h); 8192 jobs / 4 per block
  attn_kernel<<<2048, 256, 0, stream>>>(Dd, Kp, Vp);

  gemm_kernel<128, 128><<<g128, 256, 0, stream>>>(Dd, WO, bo, nullptr, Kp);

  xres_kernel<<<NROWS / 2, 256, 0, stream>>>(src, Kp, Xp, nm2);

  gemm_kernel<128, 256><<<g256, 256, 0, stream>>>(Xp, WG1, gb1, nm2, Dd);
  gemm_kernel<128, 256><<<g256, 256, 0, stream>>>(Xp, WG2, gb2, nm2, R1);

  gp_kernel<<<NROWS, 256, 0, stream>>>(Dd, R1);

  gemm_kernel<256, 128><<<g128, 256, 0, stream>>>(Dd, WG3, gb3, nullptr, Kp);

  combine_kernel<<<NROWS / 2, 256, 0, stream>>>(Xp, Kp, ln2_a, gna, nm2, nm4);

  gemm_kernel<128, 256><<<g256, 256, 0, stream>>>(Xp, WM1, mb1, nm4, Dd);

  silu_kernel<<<NROWS, 256, 0, stream>>>(Dd, sa, sb);

  gemm_kernel<256, 128><<<g128, 256, 0, stream>>>(Dd, WM2, mb2, nullptr, Vp);

  final_kernel<<<(NROWS * 128) / 256, 256, 0, stream>>>(Xp, Vp, ln3_a, nm4, (float*)d_out);
}

// Round 4
// 620.629 us; speedup vs baseline: 9.5890x; 1.0977x over previous
//
#include <hip/hip_runtime.h>
#include <hip/hip_bf16.h>
#include <math.h>

#define NROWS 25600
#define SEQL  25
#define EPSV  1e-6f

typedef __hip_bfloat16 bf16;
typedef __attribute__((ext_vector_type(4))) float f32x4;
typedef __attribute__((ext_vector_type(8))) short bf16x8;
typedef __attribute__((ext_vector_type(4))) short s16x4;
typedef unsigned int u32;

#define GLD16(gp_, lp_) __builtin_amdgcn_global_load_lds( \
    (const __attribute__((address_space(1))) u32*)(gp_), \
    (__attribute__((address_space(3))) u32*)(lp_), 16, 0, 0)

__device__ __forceinline__ float b2f(short s) {
  return __uint_as_float(((u32)(unsigned short)s) << 16);
}
__device__ __forceinline__ short f2b(float f) {
  __hip_bfloat16 h = __float2bfloat16(f);
  return *reinterpret_cast<short*>(&h);
}

// ---------------- Cl(3,0) geometric product (fp32, verified round 0) --------
__device__ __forceinline__ void gprod(const float* a, const float* b, float* r) {
  const int M[8] = {0,1,2,4,3,5,6,7};
  const int P[8] = {0,1,2,4,3,5,6,7};
#pragma unroll
  for (int i = 0; i < 8; ++i) {
    const int ma = M[i];
#pragma unroll
    for (int k = 0; k < 8; ++k) {
      const int mb = M[k];
      int par = 0;
      for (int t = ma >> 1; t; t >>= 1) par += __popc(t & mb);
      const float s = (par & 1) ? -1.f : 1.f;
      r[P[ma ^ mb]] += s * a[i] * b[k];
    }
  }
}

// ---------------- MFMA GEMM with XOR-swizzled LDS ---------------------------
// A planar [8][NROWS][KT] bf16 ; W [4 grades][ON][KT] bf16 (LN fold applied)
// Y planar [8][NROWS][ON] bf16 ; y = acc*invnm[n] + bias[col] (bias plane 0)
// grid: (NROWS/128, ON/128, 8)
// LDS layout: byte(row, c8) = row*256 + c8*16 holds global col8 = c8 ^ (row&7)
template<int KT, int ON>
__global__ __launch_bounds__(256) void gemm_kernel(
    const bf16* __restrict__ A, const bf16* __restrict__ W,
    const float* __restrict__ bias, const float* __restrict__ invnm,
    bf16* __restrict__ Y)
{
  __shared__ __align__(16) short As[128 * 128];
  __shared__ __align__(16) short Bs[128 * 128];
  const int tid  = threadIdx.x;
  const int lane = tid & 63;
  const int wid  = tid >> 6;
  const int pl   = blockIdx.z;
  const int g    = (pl == 0) ? 0 : ((pl < 4) ? 1 : ((pl < 7) ? 2 : 3));
  const size_t n0 = (size_t)blockIdx.x * 128;
  const int c0    = blockIdx.y * 128;
  const bf16* Ab = A + (size_t)pl * NROWS * KT + n0 * KT;
  const bf16* Wb = W + ((size_t)g * ON + c0) * KT;

  f32x4 acc[4][4];
#pragma unroll
  for (int i = 0; i < 4; ++i)
#pragma unroll
    for (int j = 0; j < 4; ++j) acc[i][j] = (f32x4){0.f, 0.f, 0.f, 0.f};

  const int wm = (wid & 1) * 64;
  const int wn = (wid >> 1) * 64;
  const int lg  = lane >> 4;   // 0..3
  const int c8  = lane & 15;   // 16B chunk index within row
  const int l15 = lane & 15;

  constexpr int NC = KT / 128;
#pragma unroll
  for (int kc = 0; kc < NC; ++kc) {
#pragma unroll
    for (int j = 0; j < 8; ++j) {
      const int row = wid * 32 + j * 4 + lg;
      const int sw = (c8 ^ (row & 7)) * 8;   // pre-swizzled source column
      const bf16* ga = Ab + (size_t)row * KT + kc * 128 + sw;
      const bf16* gb = Wb + (size_t)row * KT + kc * 128 + sw;
      GLD16(ga, &As[wid * 4096 + j * 512]);
      GLD16(gb, &Bs[wid * 4096 + j * 512]);
    }
    __syncthreads();
#pragma unroll
    for (int ks = 0; ks < 4; ++ks) {
      bf16x8 af[4], bg[4];
#pragma unroll
      for (int i = 0; i < 4; ++i) {
        const int rA = wm + i * 16 + l15;
        const int rB = wn + i * 16 + l15;
        af[i] = *(const bf16x8*)&As[rA * 128 + (((ks * 4 + lg) ^ (rA & 7)) * 8)];
        bg[i] = *(const bf16x8*)&Bs[rB * 128 + (((ks * 4 + lg) ^ (rB & 7)) * 8)];
      }
#pragma unroll
      for (int mi = 0; mi < 4; ++mi)
#pragma unroll
        for (int ni = 0; ni < 4; ++ni)
          acc[mi][ni] = __builtin_amdgcn_mfma_f32_16x16x32_bf16(af[mi], bg[ni], acc[mi][ni], 0, 0, 0);
    }
    if (kc + 1 < NC) __syncthreads();
  }

  const int cr = (lane >> 4) * 4;
  const int cc = lane & 15;
  bf16* Yb = Y + (size_t)pl * NROWS * ON;
#pragma unroll
  for (int mi = 0; mi < 4; ++mi) {
#pragma unroll
    for (int j = 0; j < 4; ++j) {
      const size_t n = n0 + wm + mi * 16 + cr + j;
      const float sc = invnm ? invnm[n] : 1.f;
#pragma unroll
      for (int ni = 0; ni < 4; ++ni) {
        const int colg = c0 + wn + ni * 16 + cc;
        float v = acc[mi][ni][j] * sc;
        if (pl == 0) v += bias[colg];
        Yb[n * ON + colg] = __float2bfloat16(v);
      }
    }
  }
}

// ---------------- fused weight prep: all 9 weights in one dispatch ----------
// each [O][K][4] f32 -> [4][O][K] bf16, LN scale folded into k-dim
__global__ __launch_bounds__(256) void wprep_all_kernel(
    const float* wq, const float* wk, const float* wv, const float* wo,
    const float* gw1, const float* gw2, const float* gw3,
    const float* mw1, const float* mw2,
    const float* ln1, const float* ln2, const float* ln3,
    bf16* WQ, bf16* WK, bf16* WV, bf16* WO,
    bf16* WG1, bf16* WG2, bf16* WG3, bf16* WM1, bf16* WM2)
{
  const int gid = blockIdx.x * 256 + threadIdx.x;
  const float* w; const float* ln; bf16* out; int K; int idx; int sz;
  if      (gid <  16384) { w=wq;  ln=ln1;     out=WQ;  K=128; idx=gid;          sz=16384; }
  else if (gid <  32768) { w=wk;  ln=ln1;     out=WK;  K=128; idx=gid-16384;    sz=16384; }
  else if (gid <  49152) { w=wv;  ln=ln1;     out=WV;  K=128; idx=gid-32768;    sz=16384; }
  else if (gid <  65536) { w=wo;  ln=nullptr; out=WO;  K=128; idx=gid-49152;    sz=16384; }
  else if (gid <  98304) { w=gw1; ln=ln2;     out=WG1; K=128; idx=gid-65536;    sz=32768; }
  else if (gid < 131072) { w=gw2; ln=ln2;     out=WG2; K=128; idx=gid-98304;    sz=32768; }
  else if (gid < 163840) { w=gw3; ln=nullptr; out=WG3; K=256; idx=gid-131072;   sz=32768; }
  else if (gid < 196608) { w=mw1; ln=ln3;     out=WM1; K=128; idx=gid-163840;   sz=32768; }
  else                   { w=mw2; ln=nullptr; out=WM2; K=256; idx=gid-196608;   sz=32768; }
  const int k = idx % K;
  const float s = ln ? ln[k] : 1.f;
  const float4 wv4 = *(const float4*)(w + (size_t)idx * 4);
  out[0 * sz + idx] = __float2bfloat16(wv4.x * s);
  out[1 * sz + idx] = __float2bfloat16(wv4.y * s);
  out[2 * sz + idx] = __float2bfloat16(wv4.z * s);
  out[3 * sz + idx] = __float2bfloat16(wv4.w * s);
}

// ---------------- repack: src f32 [n][128][8] -> Xp bf16 planar + 1/nm1 -----
// 4 elems (same row) per thread; 32-lane shfl row reduction (8 rows/block)
__global__ __launch_bounds__(256) void repack_kernel(
    const float* __restrict__ src, bf16* __restrict__ Xp, float* __restrict__ nminv)
{
  const int tid = threadIdx.x;
  const size_t base = ((size_t)blockIdx.x * 256 + tid) * 4; // (n,c) index
  const size_t P = (size_t)NROWS * 128;
  float v[4][8];
  const float4* sp = (const float4*)(src + base * 8);
  float part = 0.f;
#pragma unroll
  for (int e = 0; e < 4; ++e) {
    const float4 a = sp[e * 2], b = sp[e * 2 + 1];
    v[e][0]=a.x; v[e][1]=a.y; v[e][2]=a.z; v[e][3]=a.w;
    v[e][4]=b.x; v[e][5]=b.y; v[e][6]=b.z; v[e][7]=b.w;
    float ss = 0.f;
#pragma unroll
    for (int p = 0; p < 8; ++p) ss += v[e][p] * v[e][p];
    part += sqrtf(ss);
  }
#pragma unroll
  for (int p = 0; p < 8; ++p) {
    s16x4 o;
#pragma unroll
    for (int e = 0; e < 4; ++e) o[e] = f2b(v[e][p]);
    *(s16x4*)(Xp + p * P + base) = o;
  }
#pragma unroll
  for (int off = 1; off < 32; off <<= 1) part += __shfl_xor(part, off);
  if ((tid & 31) == 0) nminv[base >> 7] = 1.f / (part / 128.f + EPSV);
}

// ---------------- attention: 1 wave per (b,h); MFMA QK^T, in-reg softmax ----
__global__ __launch_bounds__(256) void attn_kernel(
    bf16* __restrict__ Q, const bf16* __restrict__ K, const bf16* __restrict__ V)
{
  __shared__ float Pld[4][32 * 36];
  const int tid  = threadIdx.x;
  const int lane = tid & 63;
  const int wid  = tid >> 6;
  const int job  = blockIdx.x * 4 + wid;
  const int b    = job >> 3;
  const int h    = job & 7;
  const size_t PS = (size_t)NROWS * 128;
  const int rowbase = b * SEQL;
  const int l15 = lane & 15;
  const int lg  = lane >> 4;

  f32x4 acc[2][2];
#pragma unroll
  for (int si = 0; si < 2; ++si)
#pragma unroll
    for (int ti = 0; ti < 2; ++ti) acc[si][ti] = (f32x4){0.f,0.f,0.f,0.f};

#pragma unroll
  for (int ks = 0; ks < 4; ++ks) {
    const int f = ks * 32 + lg * 8;
    const int p = f >> 4, d = f & 15;
    bf16x8 aq[2], bk[2];
#pragma unroll
    for (int si = 0; si < 2; ++si) {
      int s = si * 16 + l15; if (s > 24) s = 24;
      aq[si] = *(const bf16x8*)(Q + (size_t)p * PS + (size_t)(rowbase + s) * 128 + h * 16 + d);
    }
#pragma unroll
    for (int ti = 0; ti < 2; ++ti) {
      int t = ti * 16 + l15; if (t > 24) t = 24;
      bk[ti] = *(const bf16x8*)(K + (size_t)p * PS + (size_t)(rowbase + t) * 128 + h * 16 + d);
    }
#pragma unroll
    for (int si = 0; si < 2; ++si)
#pragma unroll
      for (int ti = 0; ti < 2; ++ti)
        acc[si][ti] = __builtin_amdgcn_mfma_f32_16x16x32_bf16(aq[si], bk[ti], acc[si][ti], 0, 0, 0);
  }

  const float scale = 0.08838834764831845f;
  float pv[2][2][4];
#pragma unroll
  for (int si = 0; si < 2; ++si)
#pragma unroll
    for (int ti = 0; ti < 2; ++ti)
#pragma unroll
      for (int r = 0; r < 4; ++r) {
        float v = acc[si][ti][r] * scale;
        if (ti * 16 + l15 > 24) v = -1e30f;
        pv[si][ti][r] = v;
      }
#pragma unroll
  for (int si = 0; si < 2; ++si)
#pragma unroll
    for (int r = 0; r < 4; ++r) {
      float m = fmaxf(pv[si][0][r], pv[si][1][r]);
#pragma unroll
      for (int off = 1; off < 16; off <<= 1) m = fmaxf(m, __shfl_xor(m, off));
      const float e0 = __expf(pv[si][0][r] - m);
      const float e1 = __expf(pv[si][1][r] - m);
      float sum = e0 + e1;
#pragma unroll
      for (int off = 1; off < 16; off <<= 1) sum += __shfl_xor(sum, off);
      const float inv = 1.f / sum;
      pv[si][0][r] = e0 * inv;
      pv[si][1][r] = e1 * inv;
    }

  float* Pw = &Pld[wid][0];
#pragma unroll
  for (int si = 0; si < 2; ++si)
#pragma unroll
    for (int ti = 0; ti < 2; ++ti)
#pragma unroll
      for (int r = 0; r < 4; ++r)
        Pw[(si * 16 + lg * 4 + r) * 36 + ti * 16 + l15] = pv[si][ti][r];
  __syncthreads();

  const int p2 = lane >> 3;
  const int d2 = (lane & 7) * 2;
  const bf16* vb = V + (size_t)p2 * PS + (size_t)rowbase * 128 + h * 16 + d2;
  float vlo[32], vhi[32];
#pragma unroll
  for (int t = 0; t < SEQL; ++t) {
    const __hip_bfloat162 vv = *(const __hip_bfloat162*)(vb + (size_t)t * 128);
    vlo[t] = __bfloat162float(vv.x);
    vhi[t] = __bfloat162float(vv.y);
  }
#pragma unroll
  for (int t = SEQL; t < 32; ++t) { vlo[t] = 0.f; vhi[t] = 0.f; }

  bf16* ob = Q + (size_t)p2 * PS + (size_t)rowbase * 128 + h * 16 + d2;
  for (int s = 0; s < SEQL; ++s) {
    const float4* pr = reinterpret_cast<const float4*>(&Pld[wid][s * 36]);
    float a0 = 0.f, a1 = 0.f;
#pragma unroll
    for (int t4 = 0; t4 < 8; ++t4) {
      const float4 pq = pr[t4];
      a0 += pq.x * vlo[t4*4+0] + pq.y * vlo[t4*4+1] + pq.z * vlo[t4*4+2] + pq.w * vlo[t4*4+3];
      a1 += pq.x * vhi[t4*4+0] + pq.y * vhi[t4*4+1] + pq.z * vhi[t4*4+2] + pq.w * vhi[t4*4+3];
    }
    __hip_bfloat162 o2;
    o2.x = __float2bfloat16(a0);
    o2.y = __float2bfloat16(a1);
    *(__hip_bfloat162*)(ob + (size_t)s * 128) = o2;
  }
}

// ---------------- xres = src + AO (4-wide) + 1/nm2 --------------------------
__global__ __launch_bounds__(256) void xres_kernel(
    const float* __restrict__ src, const bf16* __restrict__ AO,
    bf16* __restrict__ X, float* __restrict__ nminv)
{
  const int tid = threadIdx.x;
  const size_t base = ((size_t)blockIdx.x * 256 + tid) * 4;
  const size_t P = (size_t)NROWS * 128;
  float v[4][8];
  const float4* sp = (const float4*)(src + base * 8);
#pragma unroll
  for (int e = 0; e < 4; ++e) {
    const float4 a = sp[e * 2], b = sp[e * 2 + 1];
    v[e][0]=a.x; v[e][1]=a.y; v[e][2]=a.z; v[e][3]=a.w;
    v[e][4]=b.x; v[e][5]=b.y; v[e][6]=b.z; v[e][7]=b.w;
  }
  float part = 0.f;
  float ss[4] = {0.f, 0.f, 0.f, 0.f};
#pragma unroll
  for (int p = 0; p < 8; ++p) {
    const s16x4 av = *(const s16x4*)(AO + p * P + base);
    s16x4 o;
#pragma unroll
    for (int e = 0; e < 4; ++e) {
      v[e][p] += b2f(av[e]);
      o[e] = f2b(v[e][p]);
      ss[e] += v[e][p] * v[e][p];
    }
    *(s16x4*)(X + p * P + base) = o;
  }
#pragma unroll
  for (int e = 0; e < 4; ++e) part += sqrtf(ss[e]);
#pragma unroll
  for (int off = 1; off < 32; off <<= 1) part += __shfl_xor(part, off);
  if ((tid & 31) == 0) nminv[base >> 7] = 1.f / (part / 128.f + EPSV);
}

// ---------------- GP elementwise (4-wide, in place over XL) -----------------
__global__ __launch_bounds__(256) void gp_kernel(
    bf16* __restrict__ XL, const bf16* __restrict__ XR)
{
  const size_t base = ((size_t)blockIdx.x * 256 + threadIdx.x) * 4;
  const size_t P = (size_t)NROWS * 256;
  s16x4 av[8], bv[8], rv[8];
#pragma unroll
  for (int p = 0; p < 8; ++p) {
    av[p] = *(const s16x4*)(XL + p * P + base);
    bv[p] = *(const s16x4*)(XR + p * P + base);
  }
#pragma unroll
  for (int e = 0; e < 4; ++e) {
    float a[8], b[8], r[8] = {0.f,0.f,0.f,0.f,0.f,0.f,0.f,0.f};
#pragma unroll
    for (int p = 0; p < 8; ++p) { a[p] = b2f(av[p][e]); b[p] = b2f(bv[p][e]); }
    gprod(a, b, r);
#pragma unroll
    for (int p = 0; p < 8; ++p) rv[p][e] = f2b(r[p]);
  }
#pragma unroll
  for (int p = 0; p < 8; ++p) *(s16x4*)(XL + p * P + base) = rv[p];
}

// ---- x3 = ln2a*Xres/nm2 + gna*Gl/nmg (4-wide, shfl norms, in place) --------
__global__ __launch_bounds__(256) void combine_kernel(
    bf16* __restrict__ X, const bf16* __restrict__ Gl,
    const float* __restrict__ ln2a, const float* __restrict__ gna,
    const float* __restrict__ nm2inv, float* __restrict__ nm4inv)
{
  const int tid = threadIdx.x;
  const size_t base = ((size_t)blockIdx.x * 256 + tid) * 4;
  const size_t P = (size_t)NROWS * 128;
  const size_t n = base >> 7;
  const int c = (int)(base & 127);

  float gv[4][8];
  float ssg[4] = {0.f,0.f,0.f,0.f};
#pragma unroll
  for (int p = 0; p < 8; ++p) {
    const s16x4 g4 = *(const s16x4*)(Gl + p * P + base);
#pragma unroll
    for (int e = 0; e < 4; ++e) { gv[e][p] = b2f(g4[e]); ssg[e] += gv[e][p] * gv[e][p]; }
  }
  float partg = sqrtf(ssg[0]) + sqrtf(ssg[1]) + sqrtf(ssg[2]) + sqrtf(ssg[3]);
#pragma unroll
  for (int off = 1; off < 32; off <<= 1) partg += __shfl_xor(partg, off);
  const float invg = 1.f / (partg / 128.f + EPSV);

  const float n2 = nm2inv[n];
  float s2[4], sg[4];
#pragma unroll
  for (int e = 0; e < 4; ++e) { s2[e] = ln2a[c + e] * n2; sg[e] = gna[c + e] * invg; }

  float ss[4] = {0.f,0.f,0.f,0.f};
#pragma unroll
  for (int p = 0; p < 8; ++p) {
    const s16x4 x4 = *(const s16x4*)(X + p * P + base);
    s16x4 o;
#pragma unroll
    for (int e = 0; e < 4; ++e) {
      const float v = s2[e] * b2f(x4[e]) + sg[e] * gv[e][p];
      o[e] = f2b(v);
      ss[e] += v * v;
    }
    *(s16x4*)(X + p * P + base) = o;
  }
  float part = sqrtf(ss[0]) + sqrtf(ss[1]) + sqrtf(ss[2]) + sqrtf(ss[3]);
#pragma unroll
  for (int off = 1; off < 32; off <<= 1) part += __shfl_xor(part, off);
  if ((tid & 31) == 0) nm4inv[n] = 1.f / (part / 128.f + EPSV);
}

// ---------------- MVSiLU (4-wide, in place) ---------------------------------
__global__ __launch_bounds__(256) void silu_kernel(
    bf16* __restrict__ H, const float* __restrict__ sa, const float* __restrict__ sb)
{
  const size_t base = ((size_t)blockIdx.x * 256 + threadIdx.x) * 4;
  const int c = (int)(base & 255);
  const size_t P = (size_t)NROWS * 256;
  s16x4 hv[8];
#pragma unroll
  for (int p = 0; p < 8; ++p) hv[p] = *(const s16x4*)(H + p * P + base);
#pragma unroll
  for (int e = 0; e < 4; ++e) {
    float v[8];
#pragma unroll
    for (int p = 0; p < 8; ++p) v[p] = b2f(hv[p][e]);
    const float i0 = v[0];
    const float i1 = v[1]*v[1] + v[2]*v[2] + v[3]*v[3];
    const float i2 = v[4]*v[4] + v[5]*v[5] + v[6]*v[6];
    const float i3 = v[7]*v[7];
    const int cc = c + e;
    const float g0 = 1.f / (1.f + __expf(-(sa[cc*4+0]*i0 + sb[cc*4+0])));
    const float g1 = 1.f / (1.f + __expf(-(sa[cc*4+1]*i1 + sb[cc*4+1])));
    const float g2 = 1.f / (1.f + __expf(-(sa[cc*4+2]*i2 + sb[cc*4+2])));
    const float g3 = 1.f / (1.f + __expf(-(sa[cc*4+3]*i3 + sb[cc*4+3])));
    v[0]*=g0; v[1]*=g1; v[2]*=g1; v[3]*=g1; v[4]*=g2; v[5]*=g2; v[6]*=g2; v[7]*=g3;
#pragma unroll
    for (int p = 0; p < 8; ++p) hv[p][e] = f2b(v[p]);
  }
#pragma unroll
  for (int p = 0; p < 8; ++p) *(s16x4*)(H + p * P + base) = hv[p];
}

// ---------------- final: out = ln3a*X3/nm4 + FF (4-wide, f32 interleaved) ---
__global__ __launch_bounds__(256) void final_kernel(
    const bf16* __restrict__ X3, const bf16* __restrict__ FF,
    const float* __restrict__ ln3a, const float* __restrict__ nm4inv,
    float* __restrict__ out)
{
  const size_t base = ((size_t)blockIdx.x * 256 + threadIdx.x) * 4;
  const int c = (int)(base & 127);
  const size_t n = base >> 7;
  const size_t P = (size_t)NROWS * 128;
  const float nm = nm4inv[n];
  float o[4][8];
#pragma unroll
  for (int p = 0; p < 8; ++p) {
    const s16x4 x4 = *(const s16x4*)(X3 + p * P + base);
    const s16x4 f4 = *(const s16x4*)(FF + p * P + base);
#pragma unroll
    for (int e = 0; e < 4; ++e)
      o[e][p] = ln3a[c + e] * nm * b2f(x4[e]) + b2f(f4[e]);
  }
  float4* op = (float4*)(out + base * 8);
#pragma unroll
  for (int e = 0; e < 4; ++e) {
    float4 lo, hi;
    lo.x=o[e][0]; lo.y=o[e][1]; lo.z=o[e][2]; lo.w=o[e][3];
    hi.x=o[e][4]; hi.y=o[e][5]; hi.z=o[e][6]; hi.w=o[e][7];
    op[e * 2] = lo;
    op[e * 2 + 1] = hi;
  }
}

// ---------------- launch ----------------------------------------------------
extern "C" void kernel_launch(void* const* d_in, const int* in_sizes, int n_in,
                              void* d_out, int out_size, void* d_ws, size_t ws_size,
                              hipStream_t stream) {
  (void)in_sizes; (void)n_in; (void)out_size; (void)ws_size;
  const float* src   = (const float*)d_in[0];
  const float* ln1_a = (const float*)d_in[1];
  const float* ln2_a = (const float*)d_in[2];
  const float* ln3_a = (const float*)d_in[3];
  const float* wq = (const float*)d_in[4];  const float* bq = (const float*)d_in[5];
  const float* wk = (const float*)d_in[6];  const float* bk = (const float*)d_in[7];
  const float* wv = (const float*)d_in[8];  const float* bv = (const float*)d_in[9];
  const float* wo = (const float*)d_in[10]; const float* bo = (const float*)d_in[11];
  const float* gw1 = (const float*)d_in[12]; const float* gb1 = (const float*)d_in[13];
  const float* gw2 = (const float*)d_in[14]; const float* gb2 = (const float*)d_in[15];
  const float* gw3 = (const float*)d_in[16]; const float* gb3 = (const float*)d_in[17];
  const float* gna = (const float*)d_in[18];
  const float* mw1 = (const float*)d_in[19]; const float* mb1 = (const float*)d_in[20];
  const float* sa  = (const float*)d_in[21]; const float* sb  = (const float*)d_in[22];
  const float* mw2 = (const float*)d_in[23]; const float* mb2 = (const float*)d_in[24];

  const size_t P128 = (size_t)NROWS * 128;
  char* ws = (char*)d_ws;
  bf16* R1 = (bf16*)ws;                       // 104,857,600 B (P256 capable)
  bf16* R2 = (bf16*)(ws + 104857600);         //  52,428,800 B (P128)
  bf16* WQ = (bf16*)(ws + 157286400);
  bf16* WK = WQ + 65536;
  bf16* WV = WK + 65536;
  bf16* WO = WV + 65536;
  bf16* WG1 = WO + 65536;
  bf16* WG2 = WG1 + 131072;
  bf16* WG3 = WG2 + 131072;
  bf16* WM1 = WG3 + 131072;
  bf16* WM2 = WM1 + 131072;
  float* nm1 = (float*)(ws + 159121408);
  float* nm2 = nm1 + NROWS;
  float* nm4 = nm2 + NROWS;

  bf16* Dd = (bf16*)d_out;
  bf16* Xp = R2;
  bf16* Kp = R1;
  bf16* Vp = R1 + P128;

  wprep_all_kernel<<<896, 256, 0, stream>>>(
      wq, wk, wv, wo, gw1, gw2, gw3, mw1, mw2,
      ln1_a, ln2_a, ln3_a,
      WQ, WK, WV, WO, WG1, WG2, WG3, WM1, WM2);

  repack_kernel<<<3200, 256, 0, stream>>>(src, Xp, nm1);

  dim3 g128(NROWS / 128, 1, 8), g256(NROWS / 128, 2, 8);
  gemm_kernel<128, 128><<<g128, 256, 0, stream>>>(Xp, WQ, bq, nm1, Dd);
  gemm_kernel<128, 128><<<g128, 256, 0, stream>>>(Xp, WK, bk, nm1, Kp);
  gemm_kernel<128, 128><<<g128, 256, 0, stream>>>(Xp, WV, bv, nm1, Vp);

  attn_kernel<<<2048, 256, 0, stream>>>(Dd, Kp, Vp);

  gemm_kernel<128, 128><<<g128, 256, 0, stream>>>(Dd, WO, bo, nullptr, Kp);

  xres_kernel<<<3200, 256, 0, stream>>>(src, Kp, Xp, nm2);

  gemm_kernel<128, 256><<<g256, 256, 0, stream>>>(Xp, WG1, gb1, nm2, Dd);
  gemm_kernel<128, 256><<<g256, 256, 0, stream>>>(Xp, WG2, gb2, nm2, R1);

  gp_kernel<<<6400, 256, 0, stream>>>(Dd, R1);

  gemm_kernel<256, 128><<<g128, 256, 0, stream>>>(Dd, WG3, gb3, nullptr, Kp);

  combine_kernel<<<3200, 256, 0, stream>>>(Xp, Kp, ln2_a, gna, nm2, nm4);

  gemm_kernel<128, 256><<<g256, 256, 0, stream>>>(Xp, WM1, mb1, nm4, Dd);

  silu_kernel<<<6400, 256, 0, stream>>>(Dd, sa, sb);

  gemm_kernel<256, 128><<<g128, 256, 0, stream>>>(Dd, WM2, mb2, nullptr, Vp);

  final_kernel<<<3200, 256, 0, stream>>>(Xp, Vp, ln3_a, nm4, (float*)d_out);
}